// Round 5
// baseline (2136.782 us; speedup 1.0000x reference)
//
#include <hip/hip_runtime.h>
#include <hip/hip_bf16.h>
#include <math.h>

#define N_NODES 5000
#define N_STRUCT 50
#define PER 100
#define K_NB 24
#define N_EDGES (N_NODES*K_NB)
#define TMAX 32
#define D 128
#define FF 512
#define NTOK (N_NODES*TMAX)

typedef short bf16x8 __attribute__((ext_vector_type(8)));
typedef float f32x4  __attribute__((ext_vector_type(4)));
#define MFMA_B16(a,b,c) __builtin_amdgcn_mfma_f32_16x16x32_bf16(a,b,c,0,0,0)

__device__ __forceinline__ short f2bf(float x){           // RTNE float->bf16 bits
    unsigned u = __float_as_uint(x);
    return (short)((u + 0x7FFFu + ((u>>16)&1u)) >> 16);
}

__device__ __forceinline__ float gelu_f(float x){         // tanh-approx gelu, overflow-safe
    float E = __expf(1.5957691216057308f*(x + 0.044715f*x*x*x));  // e^{2u}
    return x - x/(E+1.f);                                  // = 0.5x(1+tanh(u))
}

__device__ __forceinline__ float cutoff_f(float r){
    if (r < 3.f) return 1.f;
    if (r >= 5.f) return 0.f;
    float x = (r-3.f)*0.5f;
    return 0.5f*(1.f + cosf(3.14159265358979323846f * x));
}

__global__ void k_zero(float* out){
    for (int i = threadIdx.x; i < N_STRUCT; i += 64) out[i] = 0.f;
}

__global__ void k_elem(const int* __restrict__ numbers, int* __restrict__ ELEM){
    int i = blockIdx.x*256 + threadIdx.x;
    if (i < N_NODES){
        int z = numbers[i];
        ELEM[i] = (z==1)?0:(z==6)?1:(z==7)?2:(z==8)?3:-1;
    }
}

__global__ void k_prep(const float* __restrict__ Wcart, const float* __restrict__ embc,
                       const float* __restrict__ embn, const float* __restrict__ Wcomp,
                       float* __restrict__ W3, float* __restrict__ ECn, float* __restrict__ ENn){
    int j = threadIdx.x; // 128
    for (int a = 0; a < 3; a++){
        float s = 0;
        for (int i = 0; i < 128; i++) s += Wcart[a*128+i]*Wcomp[i*128+j];
        W3[a*128+j] = s;
    }
    for (int sp = 0; sp < 4; sp++){
        float s1 = 0, s2 = 0;
        for (int i = 0; i < 128; i++){
            s1 += embc[sp*128+i]*Wcomp[(128+i)*128+j];
            s2 += embn[sp*128+i]*Wcomp[(256+i)*128+j];
        }
        ECn[sp*128+j] = s1; ENn[sp*128+j] = s2;
    }
}

// transpose+bf16-convert all GEMM weights into WT (dst layout [out][in], k-contiguous)
__global__ void k_wt(const float* tWq, const float* tWk, const float* tWv, const float* tWo,
                     const float* tW1, const float* tW2, const float* gWq, const float* gWk,
                     const float* gWv, const float* gWo, const float* gW1, const float* gW2,
                     const float* gct, short* __restrict__ WT){
    const int  sel[25]  = {0,0,1,1,2,2,3,3,4,4,5,5,6,6,7,7,8,8,9,9,10,10,11,11,12};
    const int  lin[25]  = {7,7,7,7,7,7,7,7,7,7,9,9,7,7,7,7,7,7,7,7,7,7,9,9,8};
    const int  lout[25] = {7,7,7,7,7,7,7,7,9,9,7,7,7,7,7,7,7,7,7,7,9,9,7,7,7};
    const int  soff[25] = {0,16384,0,16384,0,16384,0,16384,0,65536,0,65536,
                           0,16384,0,16384,0,16384,0,16384,0,65536,0,65536,0};
    const int  doff[25] = {0,16384,32768,49152,65536,81920,98304,114688,
                           131072,196608,262144,327680,
                           393216,409600,425984,442368,458752,475136,491520,507904,
                           524288,589824,655360,720896,786432};
    int gid = blockIdx.x*256 + threadIdx.x;
    if (gid >= 819200) return;
    int r = 0, base = 0;
    while (true){
        int sz = 1 << (lin[r]+lout[r]);
        if (gid < base + sz) break;
        base += sz; r++;
    }
    int d = gid - base;
    int j = d >> lin[r], i = d & ((1<<lin[r])-1);
    const float* src;
    switch (sel[r]){
        case 0: src=tWq; break; case 1: src=tWk; break; case 2: src=tWv; break; case 3: src=tWo; break;
        case 4: src=tW1; break; case 5: src=tW2; break;
        case 6: src=gWq; break; case 7: src=gWk; break; case 8: src=gWv; break; case 9: src=gWo; break;
        case 10: src=gW1; break; case 11: src=gW2; break; default: src=gct; break;
    }
    WT[doff[r] + d] = f2bf(src[soff[r] + (i<<lout[r]) + j]);
}

__global__ void k_edge(const float* __restrict__ pos, const float* __restrict__ cells,
                       const float* __restrict__ shifts, const int* __restrict__ centers,
                       const int* __restrict__ neighbors, float* __restrict__ EV,
                       float* __restrict__ RAD, int* __restrict__ CORR){
    int e = blockIdx.x*256 + threadIdx.x;
    if (e >= N_EDGES) return;
    int c = centers[e], nb = neighbors[e];
    int st = c / PER;
    const float* cell = cells + st*9;
    float s0 = shifts[e*3+0], s1 = shifts[e*3+1], s2 = shifts[e*3+2];
    float ex = pos[nb*3+0]-pos[c*3+0] + s0*cell[0]+s1*cell[3]+s2*cell[6];
    float ey = pos[nb*3+1]-pos[c*3+1] + s0*cell[1]+s1*cell[4]+s2*cell[7];
    float ez = pos[nb*3+2]-pos[c*3+2] + s0*cell[2]+s1*cell[5]+s2*cell[8];
    EV[e*3+0] = ex; EV[e*3+1] = ey; EV[e*3+2] = ez;
    RAD[e] = cutoff_f(sqrtf(ex*ex+ey*ey+ez*ez));
    int base = nb*K_NB, corr = base;
    for (int k2 = 0; k2 < K_NB; k2++){
        if (neighbors[base+k2] == c){ corr = base+k2; break; }
    }
    CORR[e] = corr;
}

__global__ void k_encode(const float* __restrict__ EV, const float* __restrict__ RAD,
                         const int* __restrict__ centers, const int* __restrict__ neighbors,
                         const int* __restrict__ ELEM, const float* __restrict__ W3,
                         const float* __restrict__ ECn, const float* __restrict__ ENn,
                         float* __restrict__ X, float* __restrict__ RADN){
    int row = blockIdx.x;   // 0..NTOK-1
    int j = threadIdx.x;    // 0..127
    int n = row >> 5, s = row & 31;
    int e = (s < K_NB) ? (n*K_NB + s) : 0;   // padding slots replicate edge 0 (nef_idx=0)
    int ec = ELEM[centers[e]], en = ELEM[neighbors[e]];
    float ev0 = EV[e*3+0], ev1 = EV[e*3+1], ev2 = EV[e*3+2];
    float v = ev0*W3[j] + ev1*W3[128+j] + ev2*W3[256+j] + ECn[ec*128+j] + ENn[en*128+j];
    X[(size_t)row*D + j] = v;
    if (j == 0) RADN[row] = (s < K_NB) ? RAD[e] : 0.f;
}

// =============== Fused 2-layer transformer: one node (32 tokens) per block ===============
// X resident in LDS (fp32) across attn+ffn+attn+ffn. Wave-ownership: head h = wave h owns
// j-slice [h*32,+32) of Q/K/V/P, so QKV->scores->softmax->PV needs no barriers.
// MFMA frag layouts (m89/m120): A[m=lane&15][k=quad*8+j]; B[k=quad*8+j][n=lane&15];
// C/D col=lane&15, row=quad*4+reg.
__global__ __launch_bounds__(256) void k_xform(float* __restrict__ X,
        const short* __restrict__ WQ, const short* __restrict__ WK,
        const short* __restrict__ WV, const short* __restrict__ WO,
        const short* __restrict__ W1, const short* __restrict__ W2,
        const float* __restrict__ LN1W, const float* __restrict__ LN1B,
        const float* __restrict__ LN2W, const float* __restrict__ LN2B,
        const float* __restrict__ B1, const float* __restrict__ B2,
        const float* __restrict__ radn){
    __shared__ __align__(16) char SM[63616];
    float* XS = (float*)SM;                 // [32][132] fp32 residual, 16896 B
    short* hh = (short*)(SM + 16896);       // [32][136] LN out bf16, 8704 B
    char*  U  = SM + 25600;                 // union region, 37888 B
    short* Qs = (short*)U;                  // [32][136] (attn) / aliased OB after scores
    short* Ks = (short*)(U + 8704);         // [32][136]
    short* VT = (short*)(U + 17408);        // [128][40] V^T, mask folded
    short* Ps = (short*)(U + 27648);        // [4][32][40]
    short* mid = (short*)U;                 // [32][520] (ffn)
    float* radl = (float*)(SM + 63488);     // [32]

    const int n = blockIdx.x, tid = threadIdx.x, lane = tid & 63, w = tid >> 6;
    const int quad = lane >> 4, l16 = lane & 15;
    float* Xn = X + (size_t)n*32*128;

    // stage X -> XS
    for (int idx = tid; idx < 32*32; idx += 256){
        int r = idx >> 5, c4 = idx & 31;
        *(f32x4*)&XS[r*132 + c4*4] = ((const f32x4*)Xn)[idx];
    }
    if (tid < 32) radl[tid] = radn[(size_t)n*32 + tid];

    // LayerNorm XS -> hh (bf16); 8 threads/row; caller must barrier before AND after
    auto layernorm = [&](const float* lw, const float* lb){
        int row = tid >> 3, l8 = tid & 7;
        f32x4 v[4];
        #pragma unroll
        for (int c = 0; c < 4; c++) v[c] = *(const f32x4*)&XS[row*132 + l8*16 + c*4];
        float s = 0, ss = 0;
        #pragma unroll
        for (int c = 0; c < 4; c++){
            #pragma unroll
            for (int k = 0; k < 4; k++){ s += v[c][k]; ss += v[c][k]*v[c][k]; }
        }
        #pragma unroll
        for (int m = 1; m < 8; m <<= 1){ s += __shfl_xor(s, m); ss += __shfl_xor(ss, m); }
        float mean = s*(1.f/128.f);
        float rstd = rsqrtf(ss*(1.f/128.f) - mean*mean + 1e-5f);
        #pragma unroll
        for (int c = 0; c < 4; c++){
            f32x4 wv4 = *(const f32x4*)&lw[l8*16 + c*4];
            f32x4 bv4 = *(const f32x4*)&lb[l8*16 + c*4];
            short4 pk;
            pk.x = f2bf((v[c][0]-mean)*rstd*wv4[0] + bv4[0]);
            pk.y = f2bf((v[c][1]-mean)*rstd*wv4[1] + bv4[1]);
            pk.z = f2bf((v[c][2]-mean)*rstd*wv4[2] + bv4[2]);
            pk.w = f2bf((v[c][3]-mean)*rstd*wv4[3] + bv4[3]);
            *(short4*)&hh[row*136 + l8*16 + c*4] = pk;
        }
    };

    for (int l = 0; l < 2; l++){
        const short* Wqt = WQ + l*16384; const short* Wkt = WK + l*16384;
        const short* Wvt = WV + l*16384; const short* Wot = WO + l*16384;
        const short* W1t = W1 + l*65536; const short* W2t = W2 + l*65536;

        // ---------------- attention ----------------
        __syncthreads();                       // XS complete (staging or prev FFN)
        layernorm(LN1W + l*128, LN1B + l*128);
        __syncthreads();                       // hh cross-wave
        {   // QKV. Q^T,K^T: D[m=j][n=t], wave m-range [w*32,+32). V: D[m=s][n=j], wave n-range.
            f32x4 z = {0.f,0.f,0.f,0.f};
            f32x4 qacc[4], kacc[4], vacc[4];
            #pragma unroll
            for (int i = 0; i < 4; i++){ qacc[i]=z; kacc[i]=z; vacc[i]=z; }
            #pragma unroll
            for (int kk = 0; kk < 4; kk++){
                bf16x8 h0 = *(const bf16x8*)&hh[(l16)*136    + kk*32 + quad*8];
                bf16x8 h1 = *(const bf16x8*)&hh[(16+l16)*136 + kk*32 + quad*8];
                #pragma unroll
                for (int mt = 0; mt < 2; mt++){
                    bf16x8 aq = *(const bf16x8*)&Wqt[(w*32+mt*16+l16)*128 + kk*32 + quad*8];
                    bf16x8 ak = *(const bf16x8*)&Wkt[(w*32+mt*16+l16)*128 + kk*32 + quad*8];
                    bf16x8 bv = *(const bf16x8*)&Wvt[(w*32+mt*16+l16)*128 + kk*32 + quad*8];
                    qacc[mt*2+0] = MFMA_B16(aq, h0, qacc[mt*2+0]);
                    qacc[mt*2+1] = MFMA_B16(aq, h1, qacc[mt*2+1]);
                    kacc[mt*2+0] = MFMA_B16(ak, h0, kacc[mt*2+0]);
                    kacc[mt*2+1] = MFMA_B16(ak, h1, kacc[mt*2+1]);
                    vacc[0*2+mt] = MFMA_B16(h0, bv, vacc[0*2+mt]);   // mt is nt for V
                    vacc[1*2+mt] = MFMA_B16(h1, bv, vacc[1*2+mt]);
                }
            }
            #pragma unroll
            for (int mt = 0; mt < 2; mt++){
                #pragma unroll
                for (int nt = 0; nt < 2; nt++){
                    {   // Q^T tile -> Qs[t][j] (scale folded); K^T -> Ks[t][j]
                        int t = nt*16 + l16, jb = w*32 + mt*16 + quad*4;
                        short4 pk;
                        pk.x = f2bf(qacc[mt*2+nt][0]*0.17677669529663689f);
                        pk.y = f2bf(qacc[mt*2+nt][1]*0.17677669529663689f);
                        pk.z = f2bf(qacc[mt*2+nt][2]*0.17677669529663689f);
                        pk.w = f2bf(qacc[mt*2+nt][3]*0.17677669529663689f);
                        *(short4*)&Qs[t*136 + jb] = pk;
                        short4 pk2;
                        pk2.x = f2bf(kacc[mt*2+nt][0]); pk2.y = f2bf(kacc[mt*2+nt][1]);
                        pk2.z = f2bf(kacc[mt*2+nt][2]); pk2.w = f2bf(kacc[mt*2+nt][3]);
                        *(short4*)&Ks[t*136 + jb] = pk2;
                    }
                    {   // V tile -> VT[j][s] * rad[s]
                        int j = w*32 + nt*16 + l16, sb = mt*16 + quad*4;
                        f32x4 r4 = *(const f32x4*)&radl[sb];
                        short4 pk;
                        pk.x = f2bf(vacc[mt*2+nt][0]*r4[0]); pk.y = f2bf(vacc[mt*2+nt][1]*r4[1]);
                        pk.z = f2bf(vacc[mt*2+nt][2]*r4[2]); pk.w = f2bf(vacc[mt*2+nt][3]*r4[3]);
                        *(short4*)&VT[j*40 + sb] = pk;
                    }
                }
            }
        }
        // NO barrier: wave h reads only its own j-slice of Qs/Ks/VT below
        {   // scores + softmax + P write; wave = head
            const int h = w;
            bf16x8 qa0 = *(const bf16x8*)&Qs[(l16)*136    + h*32 + quad*8];
            bf16x8 qa1 = *(const bf16x8*)&Qs[(16+l16)*136 + h*32 + quad*8];
            bf16x8 kb0 = *(const bf16x8*)&Ks[(l16)*136    + h*32 + quad*8];
            bf16x8 kb1 = *(const bf16x8*)&Ks[(16+l16)*136 + h*32 + quad*8];
            f32x4 z = {0.f,0.f,0.f,0.f};
            f32x4 sc00 = MFMA_B16(qa0, kb0, z), sc01 = MFMA_B16(qa0, kb1, z);
            f32x4 sc10 = MFMA_B16(qa1, kb0, z), sc11 = MFMA_B16(qa1, kb1, z);
            #pragma unroll
            for (int mt = 0; mt < 2; mt++){
                f32x4 s0 = mt ? sc10 : sc00, s1 = mt ? sc11 : sc01;
                #pragma unroll
                for (int r = 0; r < 4; r++){
                    float mx = fmaxf(s0[r], s1[r]);
                    #pragma unroll
                    for (int dlt = 1; dlt < 16; dlt <<= 1) mx = fmaxf(mx, __shfl_xor(mx, dlt));
                    float e0 = __expf(s0[r]-mx), e1 = __expf(s1[r]-mx);
                    float sm = e0 + e1;
                    #pragma unroll
                    for (int dlt = 1; dlt < 16; dlt <<= 1) sm += __shfl_xor(sm, dlt);
                    float inv = 1.f/sm;
                    int t = mt*16 + quad*4 + r;
                    Ps[h*1280 + t*40 + l16]      = f2bf(e0*inv);
                    Ps[h*1280 + t*40 + 16 + l16] = f2bf(e1*inv);
                }
            }
        }
        short* OB = Qs;   // Qs dead for this wave; OB[t][j] in own j-slice
        {   // PV: wave = head; D[m=t][n=j within head]
            const int h = w;
            bf16x8 pa0 = *(const bf16x8*)&Ps[h*1280 + (l16)*40    + quad*8];
            bf16x8 pa1 = *(const bf16x8*)&Ps[h*1280 + (16+l16)*40 + quad*8];
            bf16x8 vb0 = *(const bf16x8*)&VT[(h*32 + l16)*40      + quad*8];
            bf16x8 vb1 = *(const bf16x8*)&VT[(h*32 + 16 + l16)*40 + quad*8];
            f32x4 z = {0.f,0.f,0.f,0.f};
            f32x4 o00 = MFMA_B16(pa0, vb0, z), o01 = MFMA_B16(pa0, vb1, z);
            f32x4 o10 = MFMA_B16(pa1, vb0, z), o11 = MFMA_B16(pa1, vb1, z);
            #pragma unroll
            for (int mt = 0; mt < 2; mt++){
                #pragma unroll
                for (int nt = 0; nt < 2; nt++){
                    f32x4 ov = mt ? (nt ? o11 : o10) : (nt ? o01 : o00);
                    int j = h*32 + nt*16 + l16;
                    #pragma unroll
                    for (int r = 0; r < 4; r++){
                        int t = mt*16 + quad*4 + r;
                        OB[t*136 + j] = f2bf(ov[r]);
                    }
                }
            }
        }
        __syncthreads();   // OB cross-wave for O-proj
        {   // O-projection + residual into XS; wave n-range [w*32,+32)
            f32x4 z = {0.f,0.f,0.f,0.f};
            f32x4 oc[4] = {z,z,z,z};
            #pragma unroll
            for (int kk = 0; kk < 4; kk++){
                bf16x8 a0 = *(const bf16x8*)&OB[(l16)*136    + kk*32 + quad*8];
                bf16x8 a1 = *(const bf16x8*)&OB[(16+l16)*136 + kk*32 + quad*8];
                #pragma unroll
                for (int nt = 0; nt < 2; nt++){
                    bf16x8 bo = *(const bf16x8*)&Wot[(w*32+nt*16+l16)*128 + kk*32 + quad*8];
                    oc[0+nt] = MFMA_B16(a0, bo, oc[0+nt]);
                    oc[2+nt] = MFMA_B16(a1, bo, oc[2+nt]);
                }
            }
            #pragma unroll
            for (int mt = 0; mt < 2; mt++){
                #pragma unroll
                for (int nt = 0; nt < 2; nt++){
                    int j2 = w*32 + nt*16 + l16;
                    #pragma unroll
                    for (int r = 0; r < 4; r++){
                        int t = mt*16 + quad*4 + r;
                        XS[t*132 + j2] += oc[mt*2+nt][r];
                    }
                }
            }
        }

        // ---------------- FFN ----------------
        __syncthreads();                        // XS complete
        layernorm(LN2W + l*128, LN2B + l*128);
        __syncthreads();                        // hh cross-wave
        {   // FFN1 transposed: D[m=ff][n=t]; wave m-range [w*128,+128)
            f32x4 bb[8];
            #pragma unroll
            for (int mt = 0; mt < 8; mt++) bb[mt] = *(const f32x4*)&B1[l*512 + w*128 + mt*16 + quad*4];
            f32x4 z = {0.f,0.f,0.f,0.f};
            f32x4 acc[16];
            #pragma unroll
            for (int i = 0; i < 16; i++) acc[i] = z;
            #pragma unroll
            for (int kk = 0; kk < 4; kk++){
                bf16x8 h0 = *(const bf16x8*)&hh[(l16)*136    + kk*32 + quad*8];
                bf16x8 h1 = *(const bf16x8*)&hh[(16+l16)*136 + kk*32 + quad*8];
                #pragma unroll
                for (int mt = 0; mt < 8; mt++){
                    bf16x8 a = *(const bf16x8*)&W1t[(size_t)(w*128+mt*16+l16)*128 + kk*32 + quad*8];
                    acc[mt*2+0] = MFMA_B16(a, h0, acc[mt*2+0]);
                    acc[mt*2+1] = MFMA_B16(a, h1, acc[mt*2+1]);
                }
            }
            #pragma unroll
            for (int mt = 0; mt < 8; mt++){
                int fb = w*128 + mt*16 + quad*4;
                #pragma unroll
                for (int nt = 0; nt < 2; nt++){
                    int t = nt*16 + l16;
                    short4 pk;
                    pk.x = f2bf(gelu_f(acc[mt*2+nt][0] + bb[mt][0]));
                    pk.y = f2bf(gelu_f(acc[mt*2+nt][1] + bb[mt][1]));
                    pk.z = f2bf(gelu_f(acc[mt*2+nt][2] + bb[mt][2]));
                    pk.w = f2bf(gelu_f(acc[mt*2+nt][3] + bb[mt][3]));
                    *(short4*)&mid[t*520 + fb] = pk;
                }
            }
        }
        __syncthreads();                        // mid cross-wave
        {   // FFN2: D[m=t][n=j]; wave n-range [w*32,+32); residual in XS
            float b2v0 = B2[l*128 + w*32 + l16];
            float b2v1 = B2[l*128 + w*32 + 16 + l16];
            f32x4 z = {0.f,0.f,0.f,0.f};
            f32x4 o[4] = {z,z,z,z};
            #pragma unroll
            for (int kk = 0; kk < 16; kk++){
                bf16x8 a0 = *(const bf16x8*)&mid[(l16)*520    + kk*32 + quad*8];
                bf16x8 a1 = *(const bf16x8*)&mid[(16+l16)*520 + kk*32 + quad*8];
                #pragma unroll
                for (int nt = 0; nt < 2; nt++){
                    bf16x8 bw = *(const bf16x8*)&W2t[(size_t)(w*32+nt*16+l16)*512 + kk*32 + quad*8];
                    o[0+nt] = MFMA_B16(a0, bw, o[0+nt]);
                    o[2+nt] = MFMA_B16(a1, bw, o[2+nt]);
                }
            }
            #pragma unroll
            for (int mt = 0; mt < 2; mt++){
                #pragma unroll
                for (int nt = 0; nt < 2; nt++){
                    int j = w*32 + nt*16 + l16;
                    float bias = nt ? b2v1 : b2v0;
                    #pragma unroll
                    for (int r = 0; r < 4; r++){
                        int t = mt*16 + quad*4 + r;
                        XS[t*132 + j] += o[mt*2+nt][r] + bias;
                    }
                }
            }
        }
    }
    __syncthreads();
    // write back XS -> X
    for (int idx = tid; idx < 32*32; idx += 256){
        int r = idx >> 5, c4 = idx & 31;
        ((f32x4*)Xn)[idx] = *(const f32x4*)&XS[r*132 + c4*4];
    }
}

// ---------------- MFMA edge contraction: 32 edges per block ----------------
__global__ __launch_bounds__(256) void k_contract_mfma(const float* __restrict__ X,
        const int* __restrict__ centers, const int* __restrict__ CORR,
        const short* __restrict__ gct, float* __restrict__ Y){
    __shared__ short ab[32*264];    // [edge][256 concat feats]
    const int tid = threadIdx.x, lane = tid & 63, w = tid >> 6;
    const int quad = lane >> 4, l16 = lane & 15;
    const int e0 = blockIdx.x*32;
    for (int idx = tid; idx < 2048; idx += 256){
        int r = idx >> 6, c4 = idx & 63;
        int e = e0 + r, srcRow;
        if (c4 < 32){ int c = centers[e]; srcRow = c*32 + (e - c*K_NB); }
        else        { int ec = CORR[e]; int c = centers[ec]; srcRow = c*32 + (ec - c*K_NB); }
        float4 v = *(const float4*)&X[(size_t)srcRow*128 + (c4 & 31)*4];
        short4 pk; pk.x = f2bf(v.x); pk.y = f2bf(v.y); pk.z = f2bf(v.z); pk.w = f2bf(v.w);
        *(short4*)&ab[r*264 + c4*4] = pk;
    }
    __syncthreads();
    f32x4 z = {0.f,0.f,0.f,0.f};
    f32x4 o[4] = {z,z,z,z};
    #pragma unroll
    for (int kk = 0; kk < 8; kk++){
        bf16x8 a0 = *(const bf16x8*)&ab[(l16)*264    + kk*32 + quad*8];
        bf16x8 a1 = *(const bf16x8*)&ab[(16+l16)*264 + kk*32 + quad*8];
        #pragma unroll
        for (int nt = 0; nt < 2; nt++){
            bf16x8 bw = *(const bf16x8*)&gct[(size_t)(w*32+nt*16+l16)*256 + kk*32 + quad*8];
            o[0+nt] = MFMA_B16(a0, bw, o[0+nt]);
            o[2+nt] = MFMA_B16(a1, bw, o[2+nt]);
        }
    }
    #pragma unroll
    for (int mt = 0; mt < 2; mt++){
        #pragma unroll
        for (int nt = 0; nt < 2; nt++){
            int j = w*32 + nt*16 + l16;
            #pragma unroll
            for (int r = 0; r < 4; r++){
                int e = e0 + mt*16 + quad*4 + r;
                int c = e / K_NB, slot = e - c*K_NB;
                Y[((size_t)c*32 + slot)*128 + j] = o[mt*2+nt][r];
            }
        }
    }
}

__global__ void k_padfill(float* __restrict__ Y){
    int idx = blockIdx.x*256 + threadIdx.x;
    if (idx >= N_NODES*8*D) return;
    int j = idx & 127, rs = idx >> 7;
    int n = rs >> 3, sr = rs & 7;
    Y[((size_t)n*32 + K_NB + sr)*D + j] = Y[j];   // contracted edge 0 (nef_idx=0)
}

__global__ __launch_bounds__(256) void k_readout(const float* __restrict__ X,
        const float* __restrict__ Y, const float* __restrict__ rW,
        const float* __restrict__ radn, const int* __restrict__ ELEM,
        const float* __restrict__ cw, float* __restrict__ out){
    __shared__ float rws[128];
    __shared__ float wsum[4];
    int S = blockIdx.x >> 3, sub = blockIdx.x & 7;
    int tid = threadIdx.x, lane = tid & 63, wv = tid >> 6;
    if (tid < 128) rws[tid] = rW[tid];
    __syncthreads();
    float acc = 0.f;
    for (int r = sub*400 + wv; r < (sub+1)*400; r += 4){
        size_t row = (size_t)S*PER*32 + r;
        float rad = radn[row];
        if (rad != 0.f){
            const float* xr = X + row*D;
            const float* yr = Y + row*D;
            acc += rad * ((xr[lane]+yr[lane])*rws[lane] + (xr[lane+64]+yr[lane+64])*rws[lane+64]);
        }
    }
    if (sub == 0){
        for (int nl = tid; nl < PER; nl += 256) acc += cw[ELEM[S*PER + nl]];
    }
    #pragma unroll
    for (int m = 1; m < 64; m <<= 1) acc += __shfl_xor(acc, m);
    if (lane == 0) wsum[wv] = acc;
    __syncthreads();
    if (tid == 0) atomicAdd(&out[S], wsum[0]+wsum[1]+wsum[2]+wsum[3]);
}

extern "C" void kernel_launch(void* const* d_in, const int* in_sizes, int n_in,
                              void* d_out, int out_size, void* d_ws, size_t ws_size,
                              hipStream_t stream){
    const float* positions   = (const float*)d_in[0];
    const float* cells       = (const float*)d_in[1];
    const float* cell_shifts = (const float*)d_in[2];
    const float* enc_Wcart   = (const float*)d_in[3];
    const float* enc_emb_c   = (const float*)d_in[4];
    const float* enc_emb_n   = (const float*)d_in[5];
    const float* enc_Wcomp   = (const float*)d_in[6];
    const float* t_Wq  = (const float*)d_in[7];
    const float* t_Wk  = (const float*)d_in[8];
    const float* t_Wv  = (const float*)d_in[9];
    const float* t_Wo  = (const float*)d_in[10];
    const float* t_ln1w = (const float*)d_in[11];
    const float* t_ln1b = (const float*)d_in[12];
    const float* t_ln2w = (const float*)d_in[13];
    const float* t_ln2b = (const float*)d_in[14];
    const float* t_W1  = (const float*)d_in[15];
    const float* t_b1  = (const float*)d_in[16];
    const float* t_W2  = (const float*)d_in[17];
    const float* t_b2  = (const float*)d_in[18];
    const float* g_contr = (const float*)d_in[19];
    const float* g_Wq  = (const float*)d_in[20];
    const float* g_Wk  = (const float*)d_in[21];
    const float* g_Wv  = (const float*)d_in[22];
    const float* g_Wo  = (const float*)d_in[23];
    const float* g_ln1w = (const float*)d_in[24];
    const float* g_ln1b = (const float*)d_in[25];
    const float* g_ln2w = (const float*)d_in[26];
    const float* g_ln2b = (const float*)d_in[27];
    const float* g_W1  = (const float*)d_in[28];
    const float* g_b1  = (const float*)d_in[29];
    const float* g_W2  = (const float*)d_in[30];
    const float* g_b2  = (const float*)d_in[31];
    const float* readout_W = (const float*)d_in[32];
    const float* comp_w    = (const float*)d_in[33];
    const int* numbers   = (const int*)d_in[34];
    const int* centers   = (const int*)d_in[35];
    const int* neighbors = (const int*)d_in[36];

    float* ws = (float*)d_ws;
    float* X    = ws;                       // NTOK*D
    float* Y    = X + (size_t)NTOK*D;       // NTOK*D
    float* EV   = Y + (size_t)NTOK*D;       // N_EDGES*3
    float* RAD  = EV + (size_t)N_EDGES*3;   // N_EDGES
    float* RADN = RAD + N_EDGES;            // NTOK
    float* W3   = RADN + NTOK;              // 3*128
    float* ECn  = W3 + 3*128;               // 4*128
    float* ENn  = ECn + 4*128;              // 4*128
    int*   ELEM = (int*)(ENn + 4*128);      // N_NODES
    int*   CORR = ELEM + N_NODES;           // N_EDGES
    short* WT   = (short*)(CORR + N_EDGES); // 819200 bf16 elems

    const short *tWqt = WT,           *tWkt = WT + 32768, *tWvt = WT + 65536, *tWot = WT + 98304;
    const short *tW1t = WT + 131072,  *tW2t = WT + 262144;
    const short *gWqt = WT + 393216,  *gWkt = WT + 425984, *gWvt = WT + 458752, *gWot = WT + 491520;
    const short *gW1t = WT + 524288,  *gW2t = WT + 655360, *gctT = WT + 786432;

    k_zero<<<1, 64, 0, stream>>>((float*)d_out);
    k_elem<<<(N_NODES+255)/256, 256, 0, stream>>>(numbers, ELEM);
    k_prep<<<1, 128, 0, stream>>>(enc_Wcart, enc_emb_c, enc_emb_n, enc_Wcomp, W3, ECn, ENn);
    k_wt<<<3200, 256, 0, stream>>>(t_Wq, t_Wk, t_Wv, t_Wo, t_W1, t_W2,
                                   g_Wq, g_Wk, g_Wv, g_Wo, g_W1, g_W2, g_contr, WT);
    k_edge<<<(N_EDGES+255)/256, 256, 0, stream>>>(positions, cells, cell_shifts, centers, neighbors, EV, RAD, CORR);
    k_encode<<<NTOK, 128, 0, stream>>>(EV, RAD, centers, neighbors, ELEM, W3, ECn, ENn, X, RADN);

    k_xform<<<N_NODES, 256, 0, stream>>>(X, tWqt, tWkt, tWvt, tWot, tW1t, tW2t,
                                         t_ln1w, t_ln1b, t_ln2w, t_ln2b, t_b1, t_b2, RADN);

    k_contract_mfma<<<N_EDGES/32, 256, 0, stream>>>(X, centers, CORR, gctT, Y);
    k_padfill<<<(N_NODES*8*D+255)/256, 256, 0, stream>>>(Y);

    k_xform<<<N_NODES, 256, 0, stream>>>(Y, gWqt, gWkt, gWvt, gWot, gW1t, gW2t,
                                         g_ln1w, g_ln1b, g_ln2w, g_ln2b, g_b1, g_b2, RADN);

    k_readout<<<N_STRUCT*8, 256, 0, stream>>>(X, Y, readout_W, RADN, ELEM, comp_w, (float*)d_out);
}

// Round 6
// 1251.868 us; speedup vs baseline: 1.7069x; 1.7069x over previous
//
#include <hip/hip_runtime.h>
#include <hip/hip_bf16.h>
#include <math.h>

#define N_NODES 5000
#define N_STRUCT 50
#define PER 100
#define K_NB 24
#define N_EDGES (N_NODES*K_NB)
#define TMAX 32
#define D 128
#define FF 512
#define NTOK (N_NODES*TMAX)

typedef short bf16x8 __attribute__((ext_vector_type(8)));
typedef float f32x4  __attribute__((ext_vector_type(4)));
#define MFMA_B16(a,b,c) __builtin_amdgcn_mfma_f32_16x16x32_bf16(a,b,c,0,0,0)

__device__ __forceinline__ short f2bf(float x){           // RTNE float->bf16 bits
    unsigned u = __float_as_uint(x);
    return (short)((u + 0x7FFFu + ((u>>16)&1u)) >> 16);
}

__device__ __forceinline__ float gelu_f(float x){         // tanh-approx gelu, overflow-safe
    float E = __expf(1.5957691216057308f*(x + 0.044715f*x*x*x));  // e^{2u}
    return x - x/(E+1.f);                                  // = 0.5x(1+tanh(u))
}

__device__ __forceinline__ float cutoff_f(float r){
    if (r < 3.f) return 1.f;
    if (r >= 5.f) return 0.f;
    float x = (r-3.f)*0.5f;
    return 0.5f*(1.f + cosf(3.14159265358979323846f * x));
}

__global__ void k_zero(float* out){
    for (int i = threadIdx.x; i < N_STRUCT; i += 64) out[i] = 0.f;
}

__global__ void k_elem(const int* __restrict__ numbers, int* __restrict__ ELEM){
    int i = blockIdx.x*256 + threadIdx.x;
    if (i < N_NODES){
        int z = numbers[i];
        ELEM[i] = (z==1)?0:(z==6)?1:(z==7)?2:(z==8)?3:-1;
    }
}

__global__ void k_prep(const float* __restrict__ Wcart, const float* __restrict__ embc,
                       const float* __restrict__ embn, const float* __restrict__ Wcomp,
                       float* __restrict__ W3, float* __restrict__ ECn, float* __restrict__ ENn){
    int j = threadIdx.x; // 128
    for (int a = 0; a < 3; a++){
        float s = 0;
        for (int i = 0; i < 128; i++) s += Wcart[a*128+i]*Wcomp[i*128+j];
        W3[a*128+j] = s;
    }
    for (int sp = 0; sp < 4; sp++){
        float s1 = 0, s2 = 0;
        for (int i = 0; i < 128; i++){
            s1 += embc[sp*128+i]*Wcomp[(128+i)*128+j];
            s2 += embn[sp*128+i]*Wcomp[(256+i)*128+j];
        }
        ECn[sp*128+j] = s1; ENn[sp*128+j] = s2;
    }
}

// transpose+bf16-convert all GEMM weights into WT (dst layout [out][in], k-contiguous)
__global__ void k_wt(const float* tWq, const float* tWk, const float* tWv, const float* tWo,
                     const float* tW1, const float* tW2, const float* gWq, const float* gWk,
                     const float* gWv, const float* gWo, const float* gW1, const float* gW2,
                     const float* gct, short* __restrict__ WT){
    const int  sel[25]  = {0,0,1,1,2,2,3,3,4,4,5,5,6,6,7,7,8,8,9,9,10,10,11,11,12};
    const int  lin[25]  = {7,7,7,7,7,7,7,7,7,7,9,9,7,7,7,7,7,7,7,7,7,7,9,9,8};
    const int  lout[25] = {7,7,7,7,7,7,7,7,9,9,7,7,7,7,7,7,7,7,7,7,9,9,7,7,7};
    const int  soff[25] = {0,16384,0,16384,0,16384,0,16384,0,65536,0,65536,
                           0,16384,0,16384,0,16384,0,16384,0,65536,0,65536,0};
    const int  doff[25] = {0,16384,32768,49152,65536,81920,98304,114688,
                           131072,196608,262144,327680,
                           393216,409600,425984,442368,458752,475136,491520,507904,
                           524288,589824,655360,720896,786432};
    int gid = blockIdx.x*256 + threadIdx.x;
    if (gid >= 819200) return;
    int r = 0, base = 0;
    while (true){
        int sz = 1 << (lin[r]+lout[r]);
        if (gid < base + sz) break;
        base += sz; r++;
    }
    int d = gid - base;
    int j = d >> lin[r], i = d & ((1<<lin[r])-1);
    const float* src;
    switch (sel[r]){
        case 0: src=tWq; break; case 1: src=tWk; break; case 2: src=tWv; break; case 3: src=tWo; break;
        case 4: src=tW1; break; case 5: src=tW2; break;
        case 6: src=gWq; break; case 7: src=gWk; break; case 8: src=gWv; break; case 9: src=gWo; break;
        case 10: src=gW1; break; case 11: src=gW2; break; default: src=gct; break;
    }
    WT[doff[r] + d] = f2bf(src[soff[r] + (i<<lout[r]) + j]);
}

__global__ void k_edge(const float* __restrict__ pos, const float* __restrict__ cells,
                       const float* __restrict__ shifts, const int* __restrict__ centers,
                       const int* __restrict__ neighbors, float* __restrict__ EV,
                       float* __restrict__ RAD, int* __restrict__ CORR){
    int e = blockIdx.x*256 + threadIdx.x;
    if (e >= N_EDGES) return;
    int c = centers[e], nb = neighbors[e];
    int st = c / PER;
    const float* cell = cells + st*9;
    float s0 = shifts[e*3+0], s1 = shifts[e*3+1], s2 = shifts[e*3+2];
    float ex = pos[nb*3+0]-pos[c*3+0] + s0*cell[0]+s1*cell[3]+s2*cell[6];
    float ey = pos[nb*3+1]-pos[c*3+1] + s0*cell[1]+s1*cell[4]+s2*cell[7];
    float ez = pos[nb*3+2]-pos[c*3+2] + s0*cell[2]+s1*cell[5]+s2*cell[8];
    EV[e*3+0] = ex; EV[e*3+1] = ey; EV[e*3+2] = ez;
    RAD[e] = cutoff_f(sqrtf(ex*ex+ey*ey+ez*ez));
    int base = nb*K_NB, corr = base;
    for (int k2 = 0; k2 < K_NB; k2++){
        if (neighbors[base+k2] == c){ corr = base+k2; break; }
    }
    CORR[e] = corr;
}

__global__ void k_encode(const float* __restrict__ EV, const float* __restrict__ RAD,
                         const int* __restrict__ centers, const int* __restrict__ neighbors,
                         const int* __restrict__ ELEM, const float* __restrict__ W3,
                         const float* __restrict__ ECn, const float* __restrict__ ENn,
                         float* __restrict__ X, float* __restrict__ RADN){
    int row = blockIdx.x;   // 0..NTOK-1
    int j = threadIdx.x;    // 0..127
    int n = row >> 5, s = row & 31;
    int e = (s < K_NB) ? (n*K_NB + s) : 0;   // padding slots replicate edge 0 (nef_idx=0)
    int ec = ELEM[centers[e]], en = ELEM[neighbors[e]];
    float ev0 = EV[e*3+0], ev1 = EV[e*3+1], ev2 = EV[e*3+2];
    float v = ev0*W3[j] + ev1*W3[128+j] + ev2*W3[256+j] + ECn[ec*128+j] + ENn[en*128+j];
    X[(size_t)row*D + j] = v;
    if (j == 0) RADN[row] = (s < K_NB) ? RAD[e] : 0.f;
}

// ---------------- MFMA attention: one node (32 tokens) per block (R3-verified) ----------------
// Frag layouts (m89/m120): A[m=lane&15][k=quad*8+j]; B[k=quad*8+j][n=lane&15];
// C/D col=lane&15, row=quad*4+reg.
__global__ __launch_bounds__(256) void k_attn_mfma(float* __restrict__ X,
        const short* __restrict__ Wqt, const short* __restrict__ Wkt,
        const short* __restrict__ Wvt, const short* __restrict__ Wot,
        const float* __restrict__ lnw, const float* __restrict__ lnb,
        const float* __restrict__ radn){
    __shared__ short hh[32*136];    // LN out, [t][j]
    __shared__ short Qs[32*136];    // Q[t][j] (scaled); aliased as OB[t][j] after scores
    __shared__ short Ks[32*136];    // K[s][j]
    __shared__ short VT[128*40];    // V^T[j][s], mask folded
    __shared__ short Ps[4*32*40];   // P[h][t][s]
    __shared__ float radl[32];
    const int n = blockIdx.x, tid = threadIdx.x, lane = tid & 63, w = tid >> 6;
    const int quad = lane >> 4, l16 = lane & 15;
    float* Xn = X + (size_t)n*32*128;
    if (tid < 32) radl[tid] = radn[(size_t)n*32 + tid];
    {   // LayerNorm from global, 8 threads/row -> hh bf16
        int row = tid >> 3, l8 = tid & 7;
        f32x4 v[4];
        #pragma unroll
        for (int c = 0; c < 4; c++) v[c] = *(const f32x4*)&Xn[row*128 + l8*16 + c*4];
        float s = 0, ss = 0;
        #pragma unroll
        for (int c = 0; c < 4; c++){
            #pragma unroll
            for (int k = 0; k < 4; k++){ s += v[c][k]; ss += v[c][k]*v[c][k]; }
        }
        #pragma unroll
        for (int m = 1; m < 8; m <<= 1){ s += __shfl_xor(s, m); ss += __shfl_xor(ss, m); }
        float mean = s*(1.f/128.f);
        float rstd = rsqrtf(ss*(1.f/128.f) - mean*mean + 1e-5f);
        #pragma unroll
        for (int c = 0; c < 4; c++){
            f32x4 wv4 = *(const f32x4*)&lnw[l8*16 + c*4];
            f32x4 bv4 = *(const f32x4*)&lnb[l8*16 + c*4];
            short4 pk;
            pk.x = f2bf((v[c][0]-mean)*rstd*wv4[0] + bv4[0]);
            pk.y = f2bf((v[c][1]-mean)*rstd*wv4[1] + bv4[1]);
            pk.z = f2bf((v[c][2]-mean)*rstd*wv4[2] + bv4[2]);
            pk.w = f2bf((v[c][3]-mean)*rstd*wv4[3] + bv4[3]);
            *(short4*)&hh[row*136 + l8*16 + c*4] = pk;
        }
    }
    __syncthreads();
    {   // QKV. Q^T,K^T: D[m=j][n=t], wave m-range [w*32,+32). V: D[m=s][n=j], wave n-range.
        f32x4 z = {0.f,0.f,0.f,0.f};
        f32x4 qacc[4], kacc[4], vacc[4];
        #pragma unroll
        for (int i = 0; i < 4; i++){ qacc[i]=z; kacc[i]=z; vacc[i]=z; }
        #pragma unroll
        for (int kk = 0; kk < 4; kk++){
            bf16x8 h0 = *(const bf16x8*)&hh[(l16)*136    + kk*32 + quad*8];
            bf16x8 h1 = *(const bf16x8*)&hh[(16+l16)*136 + kk*32 + quad*8];
            #pragma unroll
            for (int mt = 0; mt < 2; mt++){
                bf16x8 aq = *(const bf16x8*)&Wqt[(w*32+mt*16+l16)*128 + kk*32 + quad*8];
                bf16x8 ak = *(const bf16x8*)&Wkt[(w*32+mt*16+l16)*128 + kk*32 + quad*8];
                bf16x8 bv = *(const bf16x8*)&Wvt[(w*32+mt*16+l16)*128 + kk*32 + quad*8];
                qacc[mt*2+0] = MFMA_B16(aq, h0, qacc[mt*2+0]);
                qacc[mt*2+1] = MFMA_B16(aq, h1, qacc[mt*2+1]);
                kacc[mt*2+0] = MFMA_B16(ak, h0, kacc[mt*2+0]);
                kacc[mt*2+1] = MFMA_B16(ak, h1, kacc[mt*2+1]);
                vacc[0*2+mt] = MFMA_B16(h0, bv, vacc[0*2+mt]);   // mt is nt for V
                vacc[1*2+mt] = MFMA_B16(h1, bv, vacc[1*2+mt]);
            }
        }
        #pragma unroll
        for (int mt = 0; mt < 2; mt++){
            #pragma unroll
            for (int nt = 0; nt < 2; nt++){
                {   // Q^T tile -> Qs[t][j] (scale folded); K^T -> Ks[t][j]
                    int t = nt*16 + l16, jb = w*32 + mt*16 + quad*4;
                    short4 pk;
                    pk.x = f2bf(qacc[mt*2+nt][0]*0.17677669529663689f);
                    pk.y = f2bf(qacc[mt*2+nt][1]*0.17677669529663689f);
                    pk.z = f2bf(qacc[mt*2+nt][2]*0.17677669529663689f);
                    pk.w = f2bf(qacc[mt*2+nt][3]*0.17677669529663689f);
                    *(short4*)&Qs[t*136 + jb] = pk;
                    short4 pk2;
                    pk2.x = f2bf(kacc[mt*2+nt][0]); pk2.y = f2bf(kacc[mt*2+nt][1]);
                    pk2.z = f2bf(kacc[mt*2+nt][2]); pk2.w = f2bf(kacc[mt*2+nt][3]);
                    *(short4*)&Ks[t*136 + jb] = pk2;
                }
                {   // V tile -> VT[j][s] * rad[s]
                    int j = w*32 + nt*16 + l16, sb = mt*16 + quad*4;
                    f32x4 r4 = *(const f32x4*)&radl[sb];
                    short4 pk;
                    pk.x = f2bf(vacc[mt*2+nt][0]*r4[0]); pk.y = f2bf(vacc[mt*2+nt][1]*r4[1]);
                    pk.z = f2bf(vacc[mt*2+nt][2]*r4[2]); pk.w = f2bf(vacc[mt*2+nt][3]*r4[3]);
                    *(short4*)&VT[j*40 + sb] = pk;
                }
            }
        }
    }
    __syncthreads();
    {   // scores + softmax + P write; wave = head
        const int h = w;
        bf16x8 qa0 = *(const bf16x8*)&Qs[(l16)*136    + h*32 + quad*8];
        bf16x8 qa1 = *(const bf16x8*)&Qs[(16+l16)*136 + h*32 + quad*8];
        bf16x8 kb0 = *(const bf16x8*)&Ks[(l16)*136    + h*32 + quad*8];
        bf16x8 kb1 = *(const bf16x8*)&Ks[(16+l16)*136 + h*32 + quad*8];
        f32x4 z = {0.f,0.f,0.f,0.f};
        f32x4 sc00 = MFMA_B16(qa0, kb0, z), sc01 = MFMA_B16(qa0, kb1, z);
        f32x4 sc10 = MFMA_B16(qa1, kb0, z), sc11 = MFMA_B16(qa1, kb1, z);
        #pragma unroll
        for (int mt = 0; mt < 2; mt++){
            f32x4 s0 = mt ? sc10 : sc00, s1 = mt ? sc11 : sc01;
            #pragma unroll
            for (int r = 0; r < 4; r++){
                float mx = fmaxf(s0[r], s1[r]);
                #pragma unroll
                for (int dlt = 1; dlt < 16; dlt <<= 1) mx = fmaxf(mx, __shfl_xor(mx, dlt));
                float e0 = __expf(s0[r]-mx), e1 = __expf(s1[r]-mx);
                float sm = e0 + e1;
                #pragma unroll
                for (int dlt = 1; dlt < 16; dlt <<= 1) sm += __shfl_xor(sm, dlt);
                float inv = 1.f/sm;
                int t = mt*16 + quad*4 + r;
                Ps[h*1280 + t*40 + l16]      = f2bf(e0*inv);
                Ps[h*1280 + t*40 + 16 + l16] = f2bf(e1*inv);
            }
        }
    }
    __syncthreads();   // Q reads done: Qs reusable as OB
    short* OB = Qs;
    {   // PV: wave = head; D[m=t][n=j within head]
        const int h = w;
        bf16x8 pa0 = *(const bf16x8*)&Ps[h*1280 + (l16)*40    + quad*8];
        bf16x8 pa1 = *(const bf16x8*)&Ps[h*1280 + (16+l16)*40 + quad*8];
        bf16x8 vb0 = *(const bf16x8*)&VT[(h*32 + l16)*40      + quad*8];
        bf16x8 vb1 = *(const bf16x8*)&VT[(h*32 + 16 + l16)*40 + quad*8];
        f32x4 z = {0.f,0.f,0.f,0.f};
        f32x4 o00 = MFMA_B16(pa0, vb0, z), o01 = MFMA_B16(pa0, vb1, z);
        f32x4 o10 = MFMA_B16(pa1, vb0, z), o11 = MFMA_B16(pa1, vb1, z);
        #pragma unroll
        for (int mt = 0; mt < 2; mt++){
            #pragma unroll
            for (int nt = 0; nt < 2; nt++){
                f32x4 ov = mt ? (nt ? o11 : o10) : (nt ? o01 : o00);
                int j = h*32 + nt*16 + l16;
                #pragma unroll
                for (int r = 0; r < 4; r++){
                    int t = mt*16 + quad*4 + r;
                    OB[t*136 + j] = f2bf(ov[r]);
                }
            }
        }
    }
    __syncthreads();
    {   // O-projection + residual; wave n-range [w*32,+32)
        f32x4 z = {0.f,0.f,0.f,0.f};
        f32x4 oc[4] = {z,z,z,z};
        #pragma unroll
        for (int kk = 0; kk < 4; kk++){
            bf16x8 a0 = *(const bf16x8*)&OB[(l16)*136    + kk*32 + quad*8];
            bf16x8 a1 = *(const bf16x8*)&OB[(16+l16)*136 + kk*32 + quad*8];
            #pragma unroll
            for (int nt = 0; nt < 2; nt++){
                bf16x8 bo = *(const bf16x8*)&Wot[(w*32+nt*16+l16)*128 + kk*32 + quad*8];
                oc[0+nt] = MFMA_B16(a0, bo, oc[0+nt]);
                oc[2+nt] = MFMA_B16(a1, bo, oc[2+nt]);
            }
        }
        #pragma unroll
        for (int mt = 0; mt < 2; mt++){
            #pragma unroll
            for (int nt = 0; nt < 2; nt++){
                int j2 = w*32 + nt*16 + l16;
                #pragma unroll
                for (int r = 0; r < 4; r++){
                    int t = mt*16 + quad*4 + r;
                    Xn[t*128 + j2] += oc[mt*2+nt][r];
                }
            }
        }
    }
}

// ======= Persistent MFMA FFN: weights in VGPRs, 512 blocks x 512 threads =======
// Wave w (of 8): FFN1 ff-slice [w*64,+64) held as 16 A-frags (64 VGPR);
//                FFN2 j-slice  [w*16,+16) held as 16 B-frags (64 VGPR).
// Loops over 32-token tiles; zero weight loads in steady state.
__global__ __launch_bounds__(512, 2) void k_ffn_p(float* __restrict__ X,
        const short* __restrict__ W1t, const short* __restrict__ W2t,
        const float* __restrict__ B1, const float* __restrict__ B2,
        const float* __restrict__ lnw, const float* __restrict__ lnb){
    __shared__ float xs[32*132];     // fp32 residual
    __shared__ short hh[32*136];     // LN out bf16
    __shared__ short mid[32*520];    // gelu out bf16
    const int tid = threadIdx.x, lane = tid & 63, w = tid >> 6;
    const int quad = lane >> 4, l16 = lane & 15;

    // ---- preload weights into registers (once) ----
    bf16x8 wA[16];                   // W1 A-frags: [mt][kk] mt<4 kk<4
    #pragma unroll
    for (int mt = 0; mt < 4; mt++)
        #pragma unroll
        for (int kk = 0; kk < 4; kk++)
            wA[mt*4+kk] = *(const bf16x8*)&W1t[(size_t)(w*64+mt*16+l16)*128 + kk*32 + quad*8];
    bf16x8 wB[16];                   // W2 B-frags: kk<16
    #pragma unroll
    for (int kk = 0; kk < 16; kk++)
        wB[kk] = *(const bf16x8*)&W2t[(size_t)(w*16+l16)*512 + kk*32 + quad*8];
    f32x4 bb1[4];
    #pragma unroll
    for (int mt = 0; mt < 4; mt++) bb1[mt] = *(const f32x4*)&B1[w*64 + mt*16 + quad*4];
    const float b2v = B2[w*16 + l16];

    for (int tile = blockIdx.x; tile < NTOK/32; tile += 512){
        float* Xg = X + (size_t)tile*32*128;
        {   // load + LN: 16 threads/row (rows 0..31), 8 floats each
            int row = tid >> 4, lc = tid & 15;
            f32x4 v0 = *(const f32x4*)&Xg[row*128 + lc*8];
            f32x4 v1 = *(const f32x4*)&Xg[row*128 + lc*8 + 4];
            *(f32x4*)&xs[row*132 + lc*8]     = v0;
            *(f32x4*)&xs[row*132 + lc*8 + 4] = v1;
            float s = 0, ss = 0;
            #pragma unroll
            for (int k = 0; k < 4; k++){ s += v0[k]+v1[k]; ss += v0[k]*v0[k]+v1[k]*v1[k]; }
            #pragma unroll
            for (int m = 1; m < 16; m <<= 1){ s += __shfl_xor(s, m); ss += __shfl_xor(ss, m); }
            float mean = s*(1.f/128.f);
            float rstd = rsqrtf(ss*(1.f/128.f) - mean*mean + 1e-5f);
            f32x4 w0 = *(const f32x4*)&lnw[lc*8], w1 = *(const f32x4*)&lnw[lc*8+4];
            f32x4 g0 = *(const f32x4*)&lnb[lc*8], g1 = *(const f32x4*)&lnb[lc*8+4];
            short4 pa, pb;
            pa.x = f2bf((v0[0]-mean)*rstd*w0[0] + g0[0]);
            pa.y = f2bf((v0[1]-mean)*rstd*w0[1] + g0[1]);
            pa.z = f2bf((v0[2]-mean)*rstd*w0[2] + g0[2]);
            pa.w = f2bf((v0[3]-mean)*rstd*w0[3] + g0[3]);
            pb.x = f2bf((v1[0]-mean)*rstd*w1[0] + g1[0]);
            pb.y = f2bf((v1[1]-mean)*rstd*w1[1] + g1[1]);
            pb.z = f2bf((v1[2]-mean)*rstd*w1[2] + g1[2]);
            pb.w = f2bf((v1[3]-mean)*rstd*w1[3] + g1[3]);
            *(short4*)&hh[row*136 + lc*8]     = pa;
            *(short4*)&hh[row*136 + lc*8 + 4] = pb;
        }
        __syncthreads();
        {   // FFN1: D[m=ff][n=t]; wave m-range [w*64,+64); 32 MFMA from reg-weights
            f32x4 z = {0.f,0.f,0.f,0.f};
            f32x4 acc[8];
            #pragma unroll
            for (int i = 0; i < 8; i++) acc[i] = z;
            #pragma unroll
            for (int kk = 0; kk < 4; kk++){
                bf16x8 h0 = *(const bf16x8*)&hh[(l16)*136    + kk*32 + quad*8];
                bf16x8 h1 = *(const bf16x8*)&hh[(16+l16)*136 + kk*32 + quad*8];
                #pragma unroll
                for (int mt = 0; mt < 4; mt++){
                    acc[mt*2+0] = MFMA_B16(wA[mt*4+kk], h0, acc[mt*2+0]);
                    acc[mt*2+1] = MFMA_B16(wA[mt*4+kk], h1, acc[mt*2+1]);
                }
            }
            #pragma unroll
            for (int mt = 0; mt < 4; mt++){
                int fb = w*64 + mt*16 + quad*4;
                #pragma unroll
                for (int nt = 0; nt < 2; nt++){
                    int t = nt*16 + l16;
                    short4 pk;
                    pk.x = f2bf(gelu_f(acc[mt*2+nt][0] + bb1[mt][0]));
                    pk.y = f2bf(gelu_f(acc[mt*2+nt][1] + bb1[mt][1]));
                    pk.z = f2bf(gelu_f(acc[mt*2+nt][2] + bb1[mt][2]));
                    pk.w = f2bf(gelu_f(acc[mt*2+nt][3] + bb1[mt][3]));
                    *(short4*)&mid[t*520 + fb] = pk;
                }
            }
        }
        __syncthreads();
        {   // FFN2: D[m=t][n=j]; wave n-range [w*16,+16); 32 MFMA from reg-weights
            f32x4 z = {0.f,0.f,0.f,0.f};
            f32x4 o0 = z, o1 = z;
            #pragma unroll
            for (int kk = 0; kk < 16; kk++){
                bf16x8 a0 = *(const bf16x8*)&mid[(l16)*520    + kk*32 + quad*8];
                bf16x8 a1 = *(const bf16x8*)&mid[(16+l16)*520 + kk*32 + quad*8];
                o0 = MFMA_B16(a0, wB[kk], o0);
                o1 = MFMA_B16(a1, wB[kk], o1);
            }
            int j = w*16 + l16;
            #pragma unroll
            for (int r = 0; r < 4; r++){
                int t0 = quad*4 + r, t1 = 16 + quad*4 + r;
                Xg[t0*128 + j] = xs[t0*132 + j] + o0[r] + b2v;
                Xg[t1*128 + j] = xs[t1*132 + j] + o1[r] + b2v;
            }
        }
        __syncthreads();   // protect xs/hh/mid before next tile
    }
}

// ---------------- MFMA edge contraction: 32 edges per block ----------------
__global__ __launch_bounds__(256) void k_contract_mfma(const float* __restrict__ X,
        const int* __restrict__ centers, const int* __restrict__ CORR,
        const short* __restrict__ gct, float* __restrict__ Y){
    __shared__ short ab[32*264];    // [edge][256 concat feats]
    const int tid = threadIdx.x, lane = tid & 63, w = tid >> 6;
    const int quad = lane >> 4, l16 = lane & 15;
    const int e0 = blockIdx.x*32;
    for (int idx = tid; idx < 2048; idx += 256){
        int r = idx >> 6, c4 = idx & 63;
        int e = e0 + r, srcRow;
        if (c4 < 32){ int c = centers[e]; srcRow = c*32 + (e - c*K_NB); }
        else        { int ec = CORR[e]; int c = centers[ec]; srcRow = c*32 + (ec - c*K_NB); }
        float4 v = *(const float4*)&X[(size_t)srcRow*128 + (c4 & 31)*4];
        short4 pk; pk.x = f2bf(v.x); pk.y = f2bf(v.y); pk.z = f2bf(v.z); pk.w = f2bf(v.w);
        *(short4*)&ab[r*264 + c4*4] = pk;
    }
    __syncthreads();
    f32x4 z = {0.f,0.f,0.f,0.f};
    f32x4 o[4] = {z,z,z,z};
    #pragma unroll
    for (int kk = 0; kk < 8; kk++){
        bf16x8 a0 = *(const bf16x8*)&ab[(l16)*264    + kk*32 + quad*8];
        bf16x8 a1 = *(const bf16x8*)&ab[(16+l16)*264 + kk*32 + quad*8];
        #pragma unroll
        for (int nt = 0; nt < 2; nt++){
            bf16x8 bw = *(const bf16x8*)&gct[(size_t)(w*32+nt*16+l16)*256 + kk*32 + quad*8];
            o[0+nt] = MFMA_B16(a0, bw, o[0+nt]);
            o[2+nt] = MFMA_B16(a1, bw, o[2+nt]);
        }
    }
    #pragma unroll
    for (int mt = 0; mt < 2; mt++){
        #pragma unroll
        for (int nt = 0; nt < 2; nt++){
            int j = w*32 + nt*16 + l16;
            #pragma unroll
            for (int r = 0; r < 4; r++){
                int e = e0 + mt*16 + quad*4 + r;
                int c = e / K_NB, slot = e - c*K_NB;
                Y[((size_t)c*32 + slot)*128 + j] = o[mt*2+nt][r];
            }
        }
    }
}

__global__ void k_padfill(float* __restrict__ Y){
    int idx = blockIdx.x*256 + threadIdx.x;
    if (idx >= N_NODES*8*D) return;
    int j = idx & 127, rs = idx >> 7;
    int n = rs >> 3, sr = rs & 7;
    Y[((size_t)n*32 + K_NB + sr)*D + j] = Y[j];   // contracted edge 0 (nef_idx=0)
}

__global__ __launch_bounds__(256) void k_readout(const float* __restrict__ X,
        const float* __restrict__ Y, const float* __restrict__ rW,
        const float* __restrict__ radn, const int* __restrict__ ELEM,
        const float* __restrict__ cw, float* __restrict__ out){
    __shared__ float rws[128];
    __shared__ float wsum[4];
    int S = blockIdx.x >> 3, sub = blockIdx.x & 7;
    int tid = threadIdx.x, lane = tid & 63, wv = tid >> 6;
    if (tid < 128) rws[tid] = rW[tid];
    __syncthreads();
    float acc = 0.f;
    for (int r = sub*400 + wv; r < (sub+1)*400; r += 4){
        size_t row = (size_t)S*PER*32 + r;
        float rad = radn[row];
        if (rad != 0.f){
            const float* xr = X + row*D;
            const float* yr = Y + row*D;
            acc += rad * ((xr[lane]+yr[lane])*rws[lane] + (xr[lane+64]+yr[lane+64])*rws[lane+64]);
        }
    }
    if (sub == 0){
        for (int nl = tid; nl < PER; nl += 256) acc += cw[ELEM[S*PER + nl]];
    }
    #pragma unroll
    for (int m = 1; m < 64; m <<= 1) acc += __shfl_xor(acc, m);
    if (lane == 0) wsum[wv] = acc;
    __syncthreads();
    if (tid == 0) atomicAdd(&out[S], wsum[0]+wsum[1]+wsum[2]+wsum[3]);
}

extern "C" void kernel_launch(void* const* d_in, const int* in_sizes, int n_in,
                              void* d_out, int out_size, void* d_ws, size_t ws_size,
                              hipStream_t stream){
    const float* positions   = (const float*)d_in[0];
    const float* cells       = (const float*)d_in[1];
    const float* cell_shifts = (const float*)d_in[2];
    const float* enc_Wcart   = (const float*)d_in[3];
    const float* enc_emb_c   = (const float*)d_in[4];
    const float* enc_emb_n   = (const float*)d_in[5];
    const float* enc_Wcomp   = (const float*)d_in[6];
    const float* t_Wq  = (const float*)d_in[7];
    const float* t_Wk  = (const float*)d_in[8];
    const float* t_Wv  = (const float*)d_in[9];
    const float* t_Wo  = (const float*)d_in[10];
    const float* t_ln1w = (const float*)d_in[11];
    const float* t_ln1b = (const float*)d_in[12];
    const float* t_ln2w = (const float*)d_in[13];
    const float* t_ln2b = (const float*)d_in[14];
    const float* t_W1  = (const float*)d_in[15];
    const float* t_b1  = (const float*)d_in[16];
    const float* t_W2  = (const float*)d_in[17];
    const float* t_b2  = (const float*)d_in[18];
    const float* g_contr = (const float*)d_in[19];
    const float* g_Wq  = (const float*)d_in[20];
    const float* g_Wk  = (const float*)d_in[21];
    const float* g_Wv  = (const float*)d_in[22];
    const float* g_Wo  = (const float*)d_in[23];
    const float* g_ln1w = (const float*)d_in[24];
    const float* g_ln1b = (const float*)d_in[25];
    const float* g_ln2w = (const float*)d_in[26];
    const float* g_ln2b = (const float*)d_in[27];
    const float* g_W1  = (const float*)d_in[28];
    const float* g_b1  = (const float*)d_in[29];
    const float* g_W2  = (const float*)d_in[30];
    const float* g_b2  = (const float*)d_in[31];
    const float* readout_W = (const float*)d_in[32];
    const float* comp_w    = (const float*)d_in[33];
    const int* numbers   = (const int*)d_in[34];
    const int* centers   = (const int*)d_in[35];
    const int* neighbors = (const int*)d_in[36];

    float* ws = (float*)d_ws;
    float* X    = ws;                       // NTOK*D
    float* Y    = X + (size_t)NTOK*D;       // NTOK*D
    float* EV   = Y + (size_t)NTOK*D;       // N_EDGES*3
    float* RAD  = EV + (size_t)N_EDGES*3;   // N_EDGES
    float* RADN = RAD + N_EDGES;            // NTOK
    float* W3   = RADN + NTOK;              // 3*128
    float* ECn  = W3 + 3*128;               // 4*128
    float* ENn  = ECn + 4*128;              // 4*128
    int*   ELEM = (int*)(ENn + 4*128);      // N_NODES
    int*   CORR = ELEM + N_NODES;           // N_EDGES
    short* WT   = (short*)(CORR + N_EDGES); // 819200 bf16 elems

    const short *tWqt = WT,           *tWkt = WT + 32768, *tWvt = WT + 65536, *tWot = WT + 98304;
    const short *tW1t = WT + 131072,  *tW2t = WT + 262144;
    const short *gWqt = WT + 393216,  *gWkt = WT + 425984, *gWvt = WT + 458752, *gWot = WT + 491520;
    const short *gW1t = WT + 524288,  *gW2t = WT + 655360, *gctT = WT + 786432;

    k_zero<<<1, 64, 0, stream>>>((float*)d_out);
    k_elem<<<(N_NODES+255)/256, 256, 0, stream>>>(numbers, ELEM);
    k_prep<<<1, 128, 0, stream>>>(enc_Wcart, enc_emb_c, enc_emb_n, enc_Wcomp, W3, ECn, ENn);
    k_wt<<<3200, 256, 0, stream>>>(t_Wq, t_Wk, t_Wv, t_Wo, t_W1, t_W2,
                                   g_Wq, g_Wk, g_Wv, g_Wo, g_W1, g_W2, g_contr, WT);
    k_edge<<<(N_EDGES+255)/256, 256, 0, stream>>>(positions, cells, cell_shifts, centers, neighbors, EV, RAD, CORR);
    k_encode<<<NTOK, 128, 0, stream>>>(EV, RAD, centers, neighbors, ELEM, W3, ECn, ENn, X, RADN);

    for (int l = 0; l < 2; l++){
        k_attn_mfma<<<N_NODES, 256, 0, stream>>>(X, tWqt + l*16384, tWkt + l*16384,
                                                 tWvt + l*16384, tWot + l*16384,
                                                 t_ln1w + l*128, t_ln1b + l*128, RADN);
        k_ffn_p<<<512, 512, 0, stream>>>(X, tW1t + l*65536, tW2t + l*65536,
                                         t_b1 + l*512, t_b2 + l*128,
                                         t_ln2w + l*128, t_ln2b + l*128);
    }

    k_contract_mfma<<<N_EDGES/32, 256, 0, stream>>>(X, centers, CORR, gctT, Y);
    k_padfill<<<(N_NODES*8*D+255)/256, 256, 0, stream>>>(Y);

    for (int l = 0; l < 2; l++){
        k_attn_mfma<<<N_NODES, 256, 0, stream>>>(Y, gWqt + l*16384, gWkt + l*16384,
                                                 gWvt + l*16384, gWot + l*16384,
                                                 g_ln1w + l*128, g_ln1b + l*128, RADN);
        k_ffn_p<<<512, 512, 0, stream>>>(Y, gW1t + l*65536, gW2t + l*65536,
                                         g_b1 + l*512, g_b2 + l*128,
                                         g_ln2w + l*128, g_ln2b + l*128);
    }

    k_readout<<<N_STRUCT*8, 256, 0, stream>>>(X, Y, readout_W, RADN, ELEM, comp_w, (float*)d_out);
}

// Round 7
// 1093.060 us; speedup vs baseline: 1.9549x; 1.1453x over previous
//
#include <hip/hip_runtime.h>
#include <hip/hip_bf16.h>
#include <math.h>

#define N_NODES 5000
#define N_STRUCT 50
#define PER 100
#define K_NB 24
#define N_EDGES (N_NODES*K_NB)
#define TMAX 32
#define D 128
#define FF 512
#define NTOK (N_NODES*TMAX)

typedef short bf16x8 __attribute__((ext_vector_type(8)));
typedef float f32x4  __attribute__((ext_vector_type(4)));
#define MFMA_B16(a,b,c) __builtin_amdgcn_mfma_f32_16x16x32_bf16(a,b,c,0,0,0)

__device__ __forceinline__ short f2bf(float x){           // round-half-up float->bf16 (2 ops)
    return (short)((__float_as_uint(x) + 0x8000u) >> 16);
}
__device__ __forceinline__ short f2bf_rn(float x){        // RTNE (weights only)
    unsigned u = __float_as_uint(x);
    return (short)((u + 0x7FFFu + ((u>>16)&1u)) >> 16);
}

__device__ __forceinline__ float gelu_f(float x){
    // x*sigmoid(2u), u = 0.79788456*(x+0.044715x^3)  == 0.5x(1+tanh(u)); 1 exp + 1 rcp
    float arg = x * fmaf(x*x, -0.07135481627f, -1.5957691216057308f);  // -2u
    return x * __builtin_amdgcn_rcpf(1.f + __expf(arg));
}

__device__ __forceinline__ float cutoff_f(float r){
    if (r < 3.f) return 1.f;
    if (r >= 5.f) return 0.f;
    float x = (r-3.f)*0.5f;
    return 0.5f*(1.f + cosf(3.14159265358979323846f * x));
}

__global__ void k_zero(float* out){
    for (int i = threadIdx.x; i < N_STRUCT; i += 64) out[i] = 0.f;
}

__global__ void k_elem(const int* __restrict__ numbers, int* __restrict__ ELEM){
    int i = blockIdx.x*256 + threadIdx.x;
    if (i < N_NODES){
        int z = numbers[i];
        ELEM[i] = (z==1)?0:(z==6)?1:(z==7)?2:(z==8)?3:-1;
    }
}

__global__ void k_prep(const float* __restrict__ Wcart, const float* __restrict__ embc,
                       const float* __restrict__ embn, const float* __restrict__ Wcomp,
                       float* __restrict__ W3, float* __restrict__ ECn, float* __restrict__ ENn){
    int j = threadIdx.x; // 128
    for (int a = 0; a < 3; a++){
        float s = 0;
        for (int i = 0; i < 128; i++) s += Wcart[a*128+i]*Wcomp[i*128+j];
        W3[a*128+j] = s;
    }
    for (int sp = 0; sp < 4; sp++){
        float s1 = 0, s2 = 0;
        for (int i = 0; i < 128; i++){
            s1 += embc[sp*128+i]*Wcomp[(128+i)*128+j];
            s2 += embn[sp*128+i]*Wcomp[(256+i)*128+j];
        }
        ECn[sp*128+j] = s1; ENn[sp*128+j] = s2;
    }
}

// transpose+bf16-convert all GEMM weights into WT (dst layout [out][in], k-contiguous)
// Wq (sel 0 and 6) gets the 1/sqrt(32) attention scale folded in.
__global__ void k_wt(const float* tWq, const float* tWk, const float* tWv, const float* tWo,
                     const float* tW1, const float* tW2, const float* gWq, const float* gWk,
                     const float* gWv, const float* gWo, const float* gW1, const float* gW2,
                     const float* gct, short* __restrict__ WT){
    const int  sel[25]  = {0,0,1,1,2,2,3,3,4,4,5,5,6,6,7,7,8,8,9,9,10,10,11,11,12};
    const int  lin[25]  = {7,7,7,7,7,7,7,7,7,7,9,9,7,7,7,7,7,7,7,7,7,7,9,9,8};
    const int  lout[25] = {7,7,7,7,7,7,7,7,9,9,7,7,7,7,7,7,7,7,7,7,9,9,7,7,7};
    const int  soff[25] = {0,16384,0,16384,0,16384,0,16384,0,65536,0,65536,
                           0,16384,0,16384,0,16384,0,16384,0,65536,0,65536,0};
    const int  doff[25] = {0,16384,32768,49152,65536,81920,98304,114688,
                           131072,196608,262144,327680,
                           393216,409600,425984,442368,458752,475136,491520,507904,
                           524288,589824,655360,720896,786432};
    int gid = blockIdx.x*256 + threadIdx.x;
    if (gid >= 819200) return;
    int r = 0, base = 0;
    while (true){
        int sz = 1 << (lin[r]+lout[r]);
        if (gid < base + sz) break;
        base += sz; r++;
    }
    int d = gid - base;
    int j = d >> lin[r], i = d & ((1<<lin[r])-1);
    const float* src;
    switch (sel[r]){
        case 0: src=tWq; break; case 1: src=tWk; break; case 2: src=tWv; break; case 3: src=tWo; break;
        case 4: src=tW1; break; case 5: src=tW2; break;
        case 6: src=gWq; break; case 7: src=gWk; break; case 8: src=gWv; break; case 9: src=gWo; break;
        case 10: src=gW1; break; case 11: src=gW2; break; default: src=gct; break;
    }
    float v = src[soff[r] + (i<<lout[r]) + j];
    if (sel[r] == 0 || sel[r] == 6) v *= 0.17677669529663689f;   // fold QK^T scale into Wq
    WT[doff[r] + d] = f2bf_rn(v);
}

__global__ void k_edge(const float* __restrict__ pos, const float* __restrict__ cells,
                       const float* __restrict__ shifts, const int* __restrict__ centers,
                       const int* __restrict__ neighbors, float* __restrict__ EV,
                       float* __restrict__ RAD, int* __restrict__ CORR){
    int e = blockIdx.x*256 + threadIdx.x;
    if (e >= N_EDGES) return;
    int c = centers[e], nb = neighbors[e];
    int st = c / PER;
    const float* cell = cells + st*9;
    float s0 = shifts[e*3+0], s1 = shifts[e*3+1], s2 = shifts[e*3+2];
    float ex = pos[nb*3+0]-pos[c*3+0] + s0*cell[0]+s1*cell[3]+s2*cell[6];
    float ey = pos[nb*3+1]-pos[c*3+1] + s0*cell[1]+s1*cell[4]+s2*cell[7];
    float ez = pos[nb*3+2]-pos[c*3+2] + s0*cell[2]+s1*cell[5]+s2*cell[8];
    EV[e*3+0] = ex; EV[e*3+1] = ey; EV[e*3+2] = ez;
    RAD[e] = cutoff_f(sqrtf(ex*ex+ey*ey+ez*ez));
    int base = nb*K_NB, corr = base;
    for (int k2 = 0; k2 < K_NB; k2++){
        if (neighbors[base+k2] == c){ corr = base+k2; break; }
    }
    CORR[e] = corr;
}

__global__ void k_encode(const float* __restrict__ EV, const float* __restrict__ RAD,
                         const int* __restrict__ centers, const int* __restrict__ neighbors,
                         const int* __restrict__ ELEM, const float* __restrict__ W3,
                         const float* __restrict__ ECn, const float* __restrict__ ENn,
                         float* __restrict__ X, float* __restrict__ RADN){
    int row = blockIdx.x;   // 0..NTOK-1
    int j = threadIdx.x;    // 0..127
    int n = row >> 5, s = row & 31;
    int e = (s < K_NB) ? (n*K_NB + s) : 0;   // padding slots replicate edge 0 (nef_idx=0)
    int ec = ELEM[centers[e]], en = ELEM[neighbors[e]];
    float ev0 = EV[e*3+0], ev1 = EV[e*3+1], ev2 = EV[e*3+2];
    float v = ev0*W3[j] + ev1*W3[128+j] + ev2*W3[256+j] + ECn[ec*128+j] + ENn[en*128+j];
    X[(size_t)row*D + j] = v;
    if (j == 0) RADN[row] = (s < K_NB) ? RAD[e] : 0.f;
}

// ======= Persistent MFMA attention: weights in VGPRs, 1024 blocks x 256 threads =======
// Wave w = head w. Holds Wq/Wk/Wv/Wo fragment slices (8 frags each, 128 VGPR total).
// Per node: 3 barriers (LN->QKV, OB->O-proj, loop-end LDS protection); all attention
// stages between are wave-private (head h reads only columns it wrote — R5-verified).
__global__ __launch_bounds__(256, 2) void k_attn_p(float* __restrict__ X,
        const short* __restrict__ Wqt, const short* __restrict__ Wkt,
        const short* __restrict__ Wvt, const short* __restrict__ Wot,
        const float* __restrict__ lnw, const float* __restrict__ lnb,
        const float* __restrict__ radn){
    __shared__ float xs[32*132];    // fp32 residual
    __shared__ short hh[32*136];    // LN out [t][j]
    __shared__ short Qs[32*136];    // Q[t][j] (pre-scaled via Wq); aliased OB after scores
    __shared__ short Ks[32*136];    // K[s][j]
    __shared__ short VT[128*40];    // V^T[j][s], mask folded
    __shared__ short Ps[4*32*40];   // P[h][t][s]
    __shared__ float radl[32];
    const int tid = threadIdx.x, lane = tid & 63, w = tid >> 6;
    const int quad = lane >> 4, l16 = lane & 15;

    // ---- preload weights into registers (once) ----
    bf16x8 wQ[8], wK[8], wV[8], wO[8];
    #pragma unroll
    for (int mt = 0; mt < 2; mt++)
        #pragma unroll
        for (int kk = 0; kk < 4; kk++){
            int ro = (w*32 + mt*16 + l16)*128 + kk*32 + quad*8;
            wQ[mt*4+kk] = *(const bf16x8*)&Wqt[ro];
            wK[mt*4+kk] = *(const bf16x8*)&Wkt[ro];
            wV[mt*4+kk] = *(const bf16x8*)&Wvt[ro];
            wO[mt*4+kk] = *(const bf16x8*)&Wot[ro];
        }

    for (int node = blockIdx.x; node < N_NODES; node += 1024){
        float* Xn = X + (size_t)node*32*128;
        {   // stage X->xs + LayerNorm->hh; 8 threads/row
            int row = tid >> 3, l8 = tid & 7;
            f32x4 v[4];
            #pragma unroll
            for (int c = 0; c < 4; c++){
                v[c] = *(const f32x4*)&Xn[row*128 + l8*16 + c*4];
                *(f32x4*)&xs[row*132 + l8*16 + c*4] = v[c];
            }
            float s = 0, ss = 0;
            #pragma unroll
            for (int c = 0; c < 4; c++){
                #pragma unroll
                for (int k = 0; k < 4; k++){ s += v[c][k]; ss += v[c][k]*v[c][k]; }
            }
            #pragma unroll
            for (int m = 1; m < 8; m <<= 1){ s += __shfl_xor(s, m); ss += __shfl_xor(ss, m); }
            float mean = s*(1.f/128.f);
            float rstd = rsqrtf(ss*(1.f/128.f) - mean*mean + 1e-5f);
            #pragma unroll
            for (int c = 0; c < 4; c++){
                f32x4 wv4 = *(const f32x4*)&lnw[l8*16 + c*4];
                f32x4 bv4 = *(const f32x4*)&lnb[l8*16 + c*4];
                short4 pk;
                pk.x = f2bf((v[c][0]-mean)*rstd*wv4[0] + bv4[0]);
                pk.y = f2bf((v[c][1]-mean)*rstd*wv4[1] + bv4[1]);
                pk.z = f2bf((v[c][2]-mean)*rstd*wv4[2] + bv4[2]);
                pk.w = f2bf((v[c][3]-mean)*rstd*wv4[3] + bv4[3]);
                *(short4*)&hh[row*136 + l8*16 + c*4] = pk;
            }
        }
        if (tid < 32) radl[tid] = radn[(size_t)node*32 + tid];
        __syncthreads();                     // (1) hh/xs/radl cross-wave

        {   // Q+K pass: D[m=j][n=t], wave m-range [w*32,+32)
            f32x4 z = {0.f,0.f,0.f,0.f};
            f32x4 qacc[4] = {z,z,z,z}, kacc[4] = {z,z,z,z};
            #pragma unroll
            for (int kk = 0; kk < 4; kk++){
                bf16x8 h0 = *(const bf16x8*)&hh[(l16)*136    + kk*32 + quad*8];
                bf16x8 h1 = *(const bf16x8*)&hh[(16+l16)*136 + kk*32 + quad*8];
                #pragma unroll
                for (int mt = 0; mt < 2; mt++){
                    qacc[mt*2+0] = MFMA_B16(wQ[mt*4+kk], h0, qacc[mt*2+0]);
                    qacc[mt*2+1] = MFMA_B16(wQ[mt*4+kk], h1, qacc[mt*2+1]);
                    kacc[mt*2+0] = MFMA_B16(wK[mt*4+kk], h0, kacc[mt*2+0]);
                    kacc[mt*2+1] = MFMA_B16(wK[mt*4+kk], h1, kacc[mt*2+1]);
                }
            }
            #pragma unroll
            for (int mt = 0; mt < 2; mt++){
                #pragma unroll
                for (int nt = 0; nt < 2; nt++){
                    int t = nt*16 + l16, jb = w*32 + mt*16 + quad*4;
                    short4 pk;
                    pk.x = f2bf(qacc[mt*2+nt][0]); pk.y = f2bf(qacc[mt*2+nt][1]);
                    pk.z = f2bf(qacc[mt*2+nt][2]); pk.w = f2bf(qacc[mt*2+nt][3]);
                    *(short4*)&Qs[t*136 + jb] = pk;
                    short4 pk2;
                    pk2.x = f2bf(kacc[mt*2+nt][0]); pk2.y = f2bf(kacc[mt*2+nt][1]);
                    pk2.z = f2bf(kacc[mt*2+nt][2]); pk2.w = f2bf(kacc[mt*2+nt][3]);
                    *(short4*)&Ks[t*136 + jb] = pk2;
                }
            }
        }
        {   // V pass: D[m=s][n=j], wave n-range [w*32,+32); rad folded
            f32x4 z = {0.f,0.f,0.f,0.f};
            f32x4 vacc[4] = {z,z,z,z};
            #pragma unroll
            for (int kk = 0; kk < 4; kk++){
                bf16x8 h0 = *(const bf16x8*)&hh[(l16)*136    + kk*32 + quad*8];
                bf16x8 h1 = *(const bf16x8*)&hh[(16+l16)*136 + kk*32 + quad*8];
                #pragma unroll
                for (int mt = 0; mt < 2; mt++){
                    vacc[0*2+mt] = MFMA_B16(h0, wV[mt*4+kk], vacc[0*2+mt]);
                    vacc[1*2+mt] = MFMA_B16(h1, wV[mt*4+kk], vacc[1*2+mt]);
                }
            }
            #pragma unroll
            for (int mt = 0; mt < 2; mt++){
                #pragma unroll
                for (int nt = 0; nt < 2; nt++){
                    int j = w*32 + nt*16 + l16, sb = mt*16 + quad*4;
                    f32x4 r4 = *(const f32x4*)&radl[sb];
                    short4 pk;
                    pk.x = f2bf(vacc[mt*2+nt][0]*r4[0]); pk.y = f2bf(vacc[mt*2+nt][1]*r4[1]);
                    pk.z = f2bf(vacc[mt*2+nt][2]*r4[2]); pk.w = f2bf(vacc[mt*2+nt][3]*r4[3]);
                    *(short4*)&VT[j*40 + sb] = pk;
                }
            }
        }
        // no barrier: wave h reads only its own columns below
        {   // scores + softmax + P write; wave = head
            const int h = w;
            bf16x8 qa0 = *(const bf16x8*)&Qs[(l16)*136    + h*32 + quad*8];
            bf16x8 qa1 = *(const bf16x8*)&Qs[(16+l16)*136 + h*32 + quad*8];
            bf16x8 kb0 = *(const bf16x8*)&Ks[(l16)*136    + h*32 + quad*8];
            bf16x8 kb1 = *(const bf16x8*)&Ks[(16+l16)*136 + h*32 + quad*8];
            f32x4 z = {0.f,0.f,0.f,0.f};
            f32x4 sc00 = MFMA_B16(qa0, kb0, z), sc01 = MFMA_B16(qa0, kb1, z);
            f32x4 sc10 = MFMA_B16(qa1, kb0, z), sc11 = MFMA_B16(qa1, kb1, z);
            #pragma unroll
            for (int mt = 0; mt < 2; mt++){
                f32x4 s0 = mt ? sc10 : sc00, s1 = mt ? sc11 : sc01;
                #pragma unroll
                for (int r = 0; r < 4; r++){
                    float mx = fmaxf(s0[r], s1[r]);
                    #pragma unroll
                    for (int dlt = 1; dlt < 16; dlt <<= 1) mx = fmaxf(mx, __shfl_xor(mx, dlt));
                    float e0 = __expf(s0[r]-mx), e1 = __expf(s1[r]-mx);
                    float sm = e0 + e1;
                    #pragma unroll
                    for (int dlt = 1; dlt < 16; dlt <<= 1) sm += __shfl_xor(sm, dlt);
                    float inv = __builtin_amdgcn_rcpf(sm);
                    int t = mt*16 + quad*4 + r;
                    Ps[h*1280 + t*40 + l16]      = f2bf(e0*inv);
                    Ps[h*1280 + t*40 + 16 + l16] = f2bf(e1*inv);
                }
            }
        }
        short* OB = Qs;
        {   // PV: wave = head; D[m=t][n=j within head]
            const int h = w;
            bf16x8 pa0 = *(const bf16x8*)&Ps[h*1280 + (l16)*40    + quad*8];
            bf16x8 pa1 = *(const bf16x8*)&Ps[h*1280 + (16+l16)*40 + quad*8];
            bf16x8 vb0 = *(const bf16x8*)&VT[(h*32 + l16)*40      + quad*8];
            bf16x8 vb1 = *(const bf16x8*)&VT[(h*32 + 16 + l16)*40 + quad*8];
            f32x4 z = {0.f,0.f,0.f,0.f};
            f32x4 o00 = MFMA_B16(pa0, vb0, z), o01 = MFMA_B16(pa0, vb1, z);
            f32x4 o10 = MFMA_B16(pa1, vb0, z), o11 = MFMA_B16(pa1, vb1, z);
            #pragma unroll
            for (int mt = 0; mt < 2; mt++){
                #pragma unroll
                for (int nt = 0; nt < 2; nt++){
                    f32x4 ov = mt ? (nt ? o11 : o10) : (nt ? o01 : o00);
                    int j = w*32 + nt*16 + l16;
                    #pragma unroll
                    for (int r = 0; r < 4; r++){
                        int t = mt*16 + quad*4 + r;
                        OB[t*136 + j] = f2bf(ov[r]);
                    }
                }
            }
        }
        __syncthreads();                     // (2) OB cross-wave
        {   // O-projection + residual from xs -> global (write-only)
            f32x4 z = {0.f,0.f,0.f,0.f};
            f32x4 oc[4] = {z,z,z,z};
            #pragma unroll
            for (int kk = 0; kk < 4; kk++){
                bf16x8 a0 = *(const bf16x8*)&OB[(l16)*136    + kk*32 + quad*8];
                bf16x8 a1 = *(const bf16x8*)&OB[(16+l16)*136 + kk*32 + quad*8];
                #pragma unroll
                for (int nt = 0; nt < 2; nt++){
                    oc[0+nt] = MFMA_B16(a0, wO[nt*4+kk], oc[0+nt]);
                    oc[2+nt] = MFMA_B16(a1, wO[nt*4+kk], oc[2+nt]);
                }
            }
            #pragma unroll
            for (int mt = 0; mt < 2; mt++){
                #pragma unroll
                for (int nt = 0; nt < 2; nt++){
                    int j2 = w*32 + nt*16 + l16;
                    #pragma unroll
                    for (int r = 0; r < 4; r++){
                        int t = mt*16 + quad*4 + r;
                        Xn[t*128 + j2] = xs[t*132 + j2] + oc[mt*2+nt][r];
                    }
                }
            }
        }
        __syncthreads();                     // (3) protect xs/hh/Qs before next node
    }
}

// ======= Persistent MFMA FFN: weights in VGPRs, 512 blocks x 512 threads =======
__global__ __launch_bounds__(512, 2) void k_ffn_p(float* __restrict__ X,
        const short* __restrict__ W1t, const short* __restrict__ W2t,
        const float* __restrict__ B1, const float* __restrict__ B2,
        const float* __restrict__ lnw, const float* __restrict__ lnb){
    __shared__ float xs[32*132];     // fp32 residual
    __shared__ short hh[32*136];     // LN out bf16
    __shared__ short mid[32*520];    // gelu out bf16
    const int tid = threadIdx.x, lane = tid & 63, w = tid >> 6;
    const int quad = lane >> 4, l16 = lane & 15;

    bf16x8 wA[16];                   // W1 A-frags
    #pragma unroll
    for (int mt = 0; mt < 4; mt++)
        #pragma unroll
        for (int kk = 0; kk < 4; kk++)
            wA[mt*4+kk] = *(const bf16x8*)&W1t[(size_t)(w*64+mt*16+l16)*128 + kk*32 + quad*8];
    bf16x8 wB[16];                   // W2 B-frags
    #pragma unroll
    for (int kk = 0; kk < 16; kk++)
        wB[kk] = *(const bf16x8*)&W2t[(size_t)(w*16+l16)*512 + kk*32 + quad*8];
    f32x4 bb1[4];
    #pragma unroll
    for (int mt = 0; mt < 4; mt++) bb1[mt] = *(const f32x4*)&B1[w*64 + mt*16 + quad*4];
    const float b2v = B2[w*16 + l16];

    for (int tile = blockIdx.x; tile < NTOK/32; tile += 512){
        float* Xg = X + (size_t)tile*32*128;
        {   // load + LN: 16 threads/row, 8 floats each
            int row = tid >> 4, lc = tid & 15;
            f32x4 v0 = *(const f32x4*)&Xg[row*128 + lc*8];
            f32x4 v1 = *(const f32x4*)&Xg[row*128 + lc*8 + 4];
            *(f32x4*)&xs[row*132 + lc*8]     = v0;
            *(f32x4*)&xs[row*132 + lc*8 + 4] = v1;
            float s = 0, ss = 0;
            #pragma unroll
            for (int k = 0; k < 4; k++){ s += v0[k]+v1[k]; ss += v0[k]*v0[k]+v1[k]*v1[k]; }
            #pragma unroll
            for (int m = 1; m < 16; m <<= 1){ s += __shfl_xor(s, m); ss += __shfl_xor(ss, m); }
            float mean = s*(1.f/128.f);
            float rstd = rsqrtf(ss*(1.f/128.f) - mean*mean + 1e-5f);
            f32x4 w0 = *(const f32x4*)&lnw[lc*8], w1 = *(const f32x4*)&lnw[lc*8+4];
            f32x4 g0 = *(const f32x4*)&lnb[lc*8], g1 = *(const f32x4*)&lnb[lc*8+4];
            short4 pa, pb;
            pa.x = f2bf((v0[0]-mean)*rstd*w0[0] + g0[0]);
            pa.y = f2bf((v0[1]-mean)*rstd*w0[1] + g0[1]);
            pa.z = f2bf((v0[2]-mean)*rstd*w0[2] + g0[2]);
            pa.w = f2bf((v0[3]-mean)*rstd*w0[3] + g0[3]);
            pb.x = f2bf((v1[0]-mean)*rstd*w1[0] + g1[0]);
            pb.y = f2bf((v1[1]-mean)*rstd*w1[1] + g1[1]);
            pb.z = f2bf((v1[2]-mean)*rstd*w1[2] + g1[2]);
            pb.w = f2bf((v1[3]-mean)*rstd*w1[3] + g1[3]);
            *(short4*)&hh[row*136 + lc*8]     = pa;
            *(short4*)&hh[row*136 + lc*8 + 4] = pb;
        }
        __syncthreads();
        {   // FFN1: D[m=ff][n=t]; wave m-range [w*64,+64)
            f32x4 z = {0.f,0.f,0.f,0.f};
            f32x4 acc[8];
            #pragma unroll
            for (int i = 0; i < 8; i++) acc[i] = z;
            #pragma unroll
            for (int kk = 0; kk < 4; kk++){
                bf16x8 h0 = *(const bf16x8*)&hh[(l16)*136    + kk*32 + quad*8];
                bf16x8 h1 = *(const bf16x8*)&hh[(16+l16)*136 + kk*32 + quad*8];
                #pragma unroll
                for (int mt = 0; mt < 4; mt++){
                    acc[mt*2+0] = MFMA_B16(wA[mt*4+kk], h0, acc[mt*2+0]);
                    acc[mt*2+1] = MFMA_B16(wA[mt*4+kk], h1, acc[mt*2+1]);
                }
            }
            #pragma unroll
            for (int mt = 0; mt < 4; mt++){
                int fb = w*64 + mt*16 + quad*4;
                #pragma unroll
                for (int nt = 0; nt < 2; nt++){
                    int t = nt*16 + l16;
                    short4 pk;
                    pk.x = f2bf(gelu_f(acc[mt*2+nt][0] + bb1[mt][0]));
                    pk.y = f2bf(gelu_f(acc[mt*2+nt][1] + bb1[mt][1]));
                    pk.z = f2bf(gelu_f(acc[mt*2+nt][2] + bb1[mt][2]));
                    pk.w = f2bf(gelu_f(acc[mt*2+nt][3] + bb1[mt][3]));
                    *(short4*)&mid[t*520 + fb] = pk;
                }
            }
        }
        __syncthreads();
        {   // FFN2: D[m=t][n=j]; wave n-range [w*16,+16); residual from xs
            f32x4 z = {0.f,0.f,0.f,0.f};
            f32x4 o0 = z, o1 = z;
            #pragma unroll
            for (int kk = 0; kk < 16; kk++){
                bf16x8 a0 = *(const bf16x8*)&mid[(l16)*520    + kk*32 + quad*8];
                bf16x8 a1 = *(const bf16x8*)&mid[(16+l16)*520 + kk*32 + quad*8];
                o0 = MFMA_B16(a0, wB[kk], o0);
                o1 = MFMA_B16(a1, wB[kk], o1);
            }
            int j = w*16 + l16;
            #pragma unroll
            for (int r = 0; r < 4; r++){
                int t0 = quad*4 + r, t1 = 16 + quad*4 + r;
                Xg[t0*128 + j] = xs[t0*132 + j] + o0[r] + b2v;
                Xg[t1*128 + j] = xs[t1*132 + j] + o1[r] + b2v;
            }
        }
        __syncthreads();
    }
}

// ---------------- MFMA edge contraction: 32 edges per block ----------------
__global__ __launch_bounds__(256) void k_contract_mfma(const float* __restrict__ X,
        const int* __restrict__ centers, const int* __restrict__ CORR,
        const short* __restrict__ gct, float* __restrict__ Y){
    __shared__ short ab[32*264];    // [edge][256 concat feats]
    const int tid = threadIdx.x, lane = tid & 63, w = tid >> 6;
    const int quad = lane >> 4, l16 = lane & 15;
    const int e0 = blockIdx.x*32;
    for (int idx = tid; idx < 2048; idx += 256){
        int r = idx >> 6, c4 = idx & 63;
        int e = e0 + r, srcRow;
        if (c4 < 32){ int c = centers[e]; srcRow = c*32 + (e - c*K_NB); }
        else        { int ec = CORR[e]; int c = centers[ec]; srcRow = c*32 + (ec - c*K_NB); }
        float4 v = *(const float4*)&X[(size_t)srcRow*128 + (c4 & 31)*4];
        short4 pk; pk.x = f2bf(v.x); pk.y = f2bf(v.y); pk.z = f2bf(v.z); pk.w = f2bf(v.w);
        *(short4*)&ab[r*264 + c4*4] = pk;
    }
    __syncthreads();
    f32x4 z = {0.f,0.f,0.f,0.f};
    f32x4 o[4] = {z,z,z,z};
    #pragma unroll
    for (int kk = 0; kk < 8; kk++){
        bf16x8 a0 = *(const bf16x8*)&ab[(l16)*264    + kk*32 + quad*8];
        bf16x8 a1 = *(const bf16x8*)&ab[(16+l16)*264 + kk*32 + quad*8];
        #pragma unroll
        for (int nt = 0; nt < 2; nt++){
            bf16x8 bw = *(const bf16x8*)&gct[(size_t)(w*32+nt*16+l16)*256 + kk*32 + quad*8];
            o[0+nt] = MFMA_B16(a0, bw, o[0+nt]);
            o[2+nt] = MFMA_B16(a1, bw, o[2+nt]);
        }
    }
    #pragma unroll
    for (int mt = 0; mt < 2; mt++){
        #pragma unroll
        for (int nt = 0; nt < 2; nt++){
            int j = w*32 + nt*16 + l16;
            #pragma unroll
            for (int r = 0; r < 4; r++){
                int e = e0 + mt*16 + quad*4 + r;
                int c = e / K_NB, slot = e - c*K_NB;
                Y[((size_t)c*32 + slot)*128 + j] = o[mt*2+nt][r];
            }
        }
    }
}

__global__ void k_padfill(float* __restrict__ Y){
    int idx = blockIdx.x*256 + threadIdx.x;
    if (idx >= N_NODES*8*D) return;
    int j = idx & 127, rs = idx >> 7;
    int n = rs >> 3, sr = rs & 7;
    Y[((size_t)n*32 + K_NB + sr)*D + j] = Y[j];   // contracted edge 0 (nef_idx=0)
}

__global__ __launch_bounds__(256) void k_readout(const float* __restrict__ X,
        const float* __restrict__ Y, const float* __restrict__ rW,
        const float* __restrict__ radn, const int* __restrict__ ELEM,
        const float* __restrict__ cw, float* __restrict__ out){
    __shared__ float rws[128];
    __shared__ float wsum[4];
    int S = blockIdx.x >> 3, sub = blockIdx.x & 7;
    int tid = threadIdx.x, lane = tid & 63, wv = tid >> 6;
    if (tid < 128) rws[tid] = rW[tid];
    __syncthreads();
    float acc = 0.f;
    for (int r = sub*400 + wv; r < (sub+1)*400; r += 4){
        size_t row = (size_t)S*PER*32 + r;
        float rad = radn[row];
        if (rad != 0.f){
            const float* xr = X + row*D;
            const float* yr = Y + row*D;
            acc += rad * ((xr[lane]+yr[lane])*rws[lane] + (xr[lane+64]+yr[lane+64])*rws[lane+64]);
        }
    }
    if (sub == 0){
        for (int nl = tid; nl < PER; nl += 256) acc += cw[ELEM[S*PER + nl]];
    }
    #pragma unroll
    for (int m = 1; m < 64; m <<= 1) acc += __shfl_xor(acc, m);
    if (lane == 0) wsum[wv] = acc;
    __syncthreads();
    if (tid == 0) atomicAdd(&out[S], wsum[0]+wsum[1]+wsum[2]+wsum[3]);
}

extern "C" void kernel_launch(void* const* d_in, const int* in_sizes, int n_in,
                              void* d_out, int out_size, void* d_ws, size_t ws_size,
                              hipStream_t stream){
    const float* positions   = (const float*)d_in[0];
    const float* cells       = (const float*)d_in[1];
    const float* cell_shifts = (const float*)d_in[2];
    const float* enc_Wcart   = (const float*)d_in[3];
    const float* enc_emb_c   = (const float*)d_in[4];
    const float* enc_emb_n   = (const float*)d_in[5];
    const float* enc_Wcomp   = (const float*)d_in[6];
    const float* t_Wq  = (const float*)d_in[7];
    const float* t_Wk  = (const float*)d_in[8];
    const float* t_Wv  = (const float*)d_in[9];
    const float* t_Wo  = (const float*)d_in[10];
    const float* t_ln1w = (const float*)d_in[11];
    const float* t_ln1b = (const float*)d_in[12];
    const float* t_ln2w = (const float*)d_in[13];
    const float* t_ln2b = (const float*)d_in[14];
    const float* t_W1  = (const float*)d_in[15];
    const float* t_b1  = (const float*)d_in[16];
    const float* t_W2  = (const float*)d_in[17];
    const float* t_b2  = (const float*)d_in[18];
    const float* g_contr = (const float*)d_in[19];
    const float* g_Wq  = (const float*)d_in[20];
    const float* g_Wk  = (const float*)d_in[21];
    const float* g_Wv  = (const float*)d_in[22];
    const float* g_Wo  = (const float*)d_in[23];
    const float* g_ln1w = (const float*)d_in[24];
    const float* g_ln1b = (const float*)d_in[25];
    const float* g_ln2w = (const float*)d_in[26];
    const float* g_ln2b = (const float*)d_in[27];
    const float* g_W1  = (const float*)d_in[28];
    const float* g_b1  = (const float*)d_in[29];
    const float* g_W2  = (const float*)d_in[30];
    const float* g_b2  = (const float*)d_in[31];
    const float* readout_W = (const float*)d_in[32];
    const float* comp_w    = (const float*)d_in[33];
    const int* numbers   = (const int*)d_in[34];
    const int* centers   = (const int*)d_in[35];
    const int* neighbors = (const int*)d_in[36];

    float* ws = (float*)d_ws;
    float* X    = ws;                       // NTOK*D
    float* Y    = X + (size_t)NTOK*D;       // NTOK*D
    float* EV   = Y + (size_t)NTOK*D;       // N_EDGES*3
    float* RAD  = EV + (size_t)N_EDGES*3;   // N_EDGES
    float* RADN = RAD + N_EDGES;            // NTOK
    float* W3   = RADN + NTOK;              // 3*128
    float* ECn  = W3 + 3*128;               // 4*128
    float* ENn  = ECn + 4*128;              // 4*128
    int*   ELEM = (int*)(ENn + 4*128);      // N_NODES
    int*   CORR = ELEM + N_NODES;           // N_EDGES
    short* WT   = (short*)(CORR + N_EDGES); // 819200 bf16 elems

    const short *tWqt = WT,           *tWkt = WT + 32768, *tWvt = WT + 65536, *tWot = WT + 98304;
    const short *tW1t = WT + 131072,  *tW2t = WT + 262144;
    const short *gWqt = WT + 393216,  *gWkt = WT + 425984, *gWvt = WT + 458752, *gWot = WT + 491520;
    const short *gW1t = WT + 524288,  *gW2t = WT + 655360, *gctT = WT + 786432;

    k_zero<<<1, 64, 0, stream>>>((float*)d_out);
    k_elem<<<(N_NODES+255)/256, 256, 0, stream>>>(numbers, ELEM);
    k_prep<<<1, 128, 0, stream>>>(enc_Wcart, enc_emb_c, enc_emb_n, enc_Wcomp, W3, ECn, ENn);
    k_wt<<<3200, 256, 0, stream>>>(t_Wq, t_Wk, t_Wv, t_Wo, t_W1, t_W2,
                                   g_Wq, g_Wk, g_Wv, g_Wo, g_W1, g_W2, g_contr, WT);
    k_edge<<<(N_EDGES+255)/256, 256, 0, stream>>>(positions, cells, cell_shifts, centers, neighbors, EV, RAD, CORR);
    k_encode<<<NTOK, 128, 0, stream>>>(EV, RAD, centers, neighbors, ELEM, W3, ECn, ENn, X, RADN);

    for (int l = 0; l < 2; l++){
        k_attn_p<<<1024, 256, 0, stream>>>(X, tWqt + l*16384, tWkt + l*16384,
                                           tWvt + l*16384, tWot + l*16384,
                                           t_ln1w + l*128, t_ln1b + l*128, RADN);
        k_ffn_p<<<512, 512, 0, stream>>>(X, tW1t + l*65536, tW2t + l*65536,
                                         t_b1 + l*512, t_b2 + l*128,
                                         t_ln2w + l*128, t_ln2b + l*128);
    }

    k_contract_mfma<<<N_EDGES/32, 256, 0, stream>>>(X, centers, CORR, gctT, Y);
    k_padfill<<<(N_NODES*8*D+255)/256, 256, 0, stream>>>(Y);

    for (int l = 0; l < 2; l++){
        k_attn_p<<<1024, 256, 0, stream>>>(Y, gWqt + l*16384, gWkt + l*16384,
                                           gWvt + l*16384, gWot + l*16384,
                                           g_ln1w + l*128, g_ln1b + l*128, RADN);
        k_ffn_p<<<512, 512, 0, stream>>>(Y, gW1t + l*65536, gW2t + l*65536,
                                         g_b1 + l*512, g_b2 + l*128,
                                         g_ln2w + l*128, g_ln2b + l*128);
    }

    k_readout<<<N_STRUCT*8, 256, 0, stream>>>(X, Y, readout_W, RADN, ELEM, comp_w, (float*)d_out);
}